// Round 4
// baseline (6285.815 us; speedup 1.0000x reference)
//
#include <hip/hip_runtime.h>
#include <math.h>
#include <stdint.h>

// Replicate XLA numerics: no FMA contraction anywhere.
#pragma clang fp contract(off)

// ---------------- problem constants ----------------
// x_old: (32,3,224,224) f32; x/out: (32,64,56,56) f32
#define NDIST   3612672   // 32*9*112*112 = 882*4096
#define NPMAP   401408    // 32*112*112
#define NPOOL   100352    // 32*3136
#define NSAMP_T 641024    // 313 * 2048 (one task per (s,r))
#define NTASK2  1282048   // NSAMP_T * 2 half-row tasks
#define NMEANB  882       // k_mean1 blocks (4096 elems each)

__device__ __align__(16) float g_dist[NDIST];
__device__ __align__(16) float g_pmap[NPMAP];
__device__ __align__(16) float g_pooled[NPOOL];
__device__ __align__(16) float g_logits[NPOOL];
__device__ __align__(16) float g_pM[NTASK2];
__device__ __align__(16) int   g_pJ[NTASK2];
__device__ float g_partial[NMEANB];
__device__ float g_lmax[32];
__device__ float g_mean[1];
__device__ int   g_sij[18];

// ---------------- NumPy SeedSequence(0) + PCG64 + 32-bit buffered Lemire ----------------
// VERIFIED R6 (absmax=0): mix = x*L - y*R; low-half-first next32; Lemire-32 thr=4;
// initstate = (gs[0]<<64)|gs[1].
__device__ __forceinline__ uint32_t ss_hash(uint32_t value, uint32_t& hc) {
  value ^= hc; hc *= 0x931e8875u; value *= hc; value ^= value >> 16; return value;
}
__device__ __forceinline__ uint32_t ss_mix(uint32_t x, uint32_t y) {
  uint32_t r = x * 0xca01f9ddu - y * 0x4973f715u;   // multiply-SUBTRACT (numpy mix)
  r ^= r >> 16; return r;
}

__global__ void k_rng() {
  if (threadIdx.x != 0 || blockIdx.x != 0) return;
  uint32_t pool[4];
  uint32_t hc = 0x43b0d7e5u;                       // INIT_A
  for (int i = 0; i < 4; ++i) pool[i] = ss_hash(0u, hc);
  for (int is = 0; is < 4; ++is)
    for (int id = 0; id < 4; ++id)
      if (is != id) pool[id] = ss_mix(pool[id], ss_hash(pool[is], hc));
  uint32_t hb = 0x8b51f9ddu;                       // INIT_B
  uint32_t w[8];
  for (int i = 0; i < 8; ++i) {
    uint32_t dv = pool[i & 3];
    dv ^= hb; hb *= 0x58f38dedu; dv *= hb; dv ^= dv >> 16; w[i] = dv;
  }
  uint64_t gs[4];
  for (int i = 0; i < 4; ++i) gs[i] = (uint64_t)w[2*i] | ((uint64_t)w[2*i+1] << 32);
  const __uint128_t MUL = (((__uint128_t)0x2360ED051FC65DA4ull) << 64) | 0x4385DF649FCCF645ull;
  __uint128_t initstate = (((__uint128_t)gs[0]) << 64) | gs[1];
  __uint128_t initseq   = (((__uint128_t)gs[2]) << 64) | gs[3];
  __uint128_t inc   = (initseq << 1) | 1;
  __uint128_t state = 0;
  state = state * MUL + inc;
  state += initstate;
  state = state * MUL + inc;

  bool has32 = false; uint32_t saved32 = 0;
  auto next32 = [&]() -> uint32_t {
    if (has32) { has32 = false; return saved32; }
    state = state * MUL + inc;
    uint64_t xo = (uint64_t)(state >> 64) ^ (uint64_t)state;
    uint32_t rot = (uint32_t)(state >> 122) & 63u;
    uint64_t v = (xo >> rot) | (xo << ((64u - rot) & 63u));   // rotr
    has32 = true; saved32 = (uint32_t)(v >> 32);              // high half buffered
    return (uint32_t)v;                                       // low half first
  };

  for (int k = 0; k < 18; ++k) {
    uint64_t m = (uint64_t)next32() * 7ull;
    uint32_t leftover = (uint32_t)m;
    if (leftover < 7u) {
      while (leftover < 4u) { m = (uint64_t)next32() * 7ull; leftover = (uint32_t)m; }
    }
    g_sij[k] = (int)(uint32_t)(m >> 32) - 3;
  }
}

// ---------------- distance: per-patch squared-diff 7x7 stride-2 window sums ----------------
__global__ __launch_bounds__(256) void k_dist(const float* __restrict__ xold) {
  int idx = blockIdx.x * 256 + threadIdx.x;
  if (idx >= NDIST) return;
  int ox = idx % 112; int tt = idx / 112;
  int oy = tt % 112;  tt /= 112;
  int p = tt % 9;     int b = tt / 9;
  int si = g_sij[p], sj = g_sij[9 + p];
  const float* xb = xold + (size_t)b * 3 * 224 * 224;
  float acc = 0.f;
  for (int kh = 0; kh < 7; ++kh) {
    int hb = 2 * oy + kh - 3;
    int hs = hb + si;
    for (int kw = 0; kw < 7; ++kw) {
      int wb = 2 * ox + kw - 3;
      int wsf = wb + sj;
      float s = 0.f;
      for (int c = 0; c < 3; ++c) {
        const float* xc = xb + c * 224 * 224;
        float bv = (hb >= 0 && hb < 224 && wb >= 0 && wb < 224) ? xc[hb * 224 + wb] : 0.f;
        float sv = (hs >= 0 && hs < 224 && wsf >= 0 && wsf < 224) ? xc[hs * 224 + wsf] : 0.f;
        float d = bv - sv;
        s = s + d * d;              // channel sum, in order
      }
      acc = acc + s;                // window sum, row-major order
    }
  }
  g_dist[idx] = acc;
}

// ---------------- global mean: deterministic two-stage reduce ----------------
__global__ __launch_bounds__(256) void k_mean1() {
  __shared__ float red[256];
  int base = blockIdx.x * 4096;
  float acc = 0.f;
  #pragma unroll
  for (int i = 0; i < 4; ++i) {
    float4 v = *(const float4*)(g_dist + base + threadIdx.x * 4 + i * 1024);
    acc = acc + v.x + v.y + v.z + v.w;
  }
  red[threadIdx.x] = acc;
  __syncthreads();
  for (int s = 128; s > 0; s >>= 1) {
    if (threadIdx.x < s) red[threadIdx.x] += red[threadIdx.x + s];
    __syncthreads();
  }
  if (threadIdx.x == 0) g_partial[blockIdx.x] = red[0];
}
__global__ void k_mean2() {
  if (threadIdx.x != 0 || blockIdx.x != 0) return;
  float acc = 0.f;
  for (int i = 0; i < NMEANB; ++i) acc = acc + g_partial[i];
  g_mean[0] = acc / 3612672.0f;
}

// ---------------- pmap = ((sum_p exp(-d/m/2))/9)^2 ----------------
__global__ __launch_bounds__(256) void k_prob1() {
  int idx = blockIdx.x * 256 + threadIdx.x;
  if (idx >= NPMAP) return;
  int xy = idx % 12544; int b = idx / 12544;
  float m = g_mean[0];
  float ssum = 0.f;
  for (int p = 0; p < 9; ++p) {
    float d = g_dist[(size_t)(b * 9 + p) * 12544 + xy];
    float t = (-d / m) / 2.0f;                      // / BW^2 == /1.0 exact
    float e = expf(t);
    ssum = ssum + e;
  }
  float q = ssum / 9.0f;
  g_pmap[idx] = q * q;                              // ** (1/TEMP) == ^2
}

// ---------------- min-pool 3x3 stride 2 pad 1 ----------------
__global__ __launch_bounds__(256) void k_pool() {
  int idx = blockIdx.x * 256 + threadIdx.x;
  if (idx >= NPOOL) return;
  int ox = idx % 56; int tt = idx / 56;
  int oy = tt % 56;  int b = tt / 56;
  float mn = INFINITY;
  for (int kh = 0; kh < 3; ++kh) {
    int y = 2 * oy - 1 + kh; if (y < 0 || y >= 112) continue;
    for (int kw = 0; kw < 3; ++kw) {
      int x = 2 * ox - 1 + kw; if (x < 0 || x >= 112) continue;
      mn = fminf(mn, g_pmap[(size_t)(b * 112 + y) * 112 + x]);
    }
  }
  g_pooled[idx] = mn;
}

// ---------------- per-b row sum, logits = logf(p/S + 1e-8), row max ----------------
__global__ void k_norm() {
  int b = threadIdx.x;
  if (b >= 32 || blockIdx.x != 0) return;
  const float* P = g_pooled + b * 3136;
  float s = 0.f;
  for (int i = 0; i < 3136; ++i) s = s + P[i];
  float lm = -INFINITY;
  for (int i = 0; i < 3136; ++i) {
    float fl = P[i] / s;
    float lg = logf(fl + 1e-8f);
    g_logits[b * 3136 + i] = lg;
    lm = fmaxf(lm, lg);
  }
  g_lmax[b] = lm;
}

// ---------------- out = x ----------------
__global__ __launch_bounds__(256) void k_copy(const float4* __restrict__ x, float4* __restrict__ out) {
  int i = blockIdx.x * 256 + threadIdx.x;           // 1,605,632 float4 exactly
  out[i] = x[i];
}

// ---------------- JAX threefry2x32, key = (0, 42), partitionable 32-bit bits ----------------
__device__ __forceinline__ uint32_t rotl32(uint32_t x, int r) { return (x << r) | (x >> (32 - r)); }
__device__ __forceinline__ void threefry2x32(uint32_t x0, uint32_t x1, uint32_t& o0, uint32_t& o1) {
  const uint32_t ks0 = 0u, ks1 = 42u, ks2 = 0x1BD11BDAu ^ 0u ^ 42u;
  x0 += ks0; x1 += ks1;
#define TFR(r) { x0 += x1; x1 = rotl32(x1, (r)); x1 ^= x0; }
  TFR(13) TFR(15) TFR(26) TFR(6)  x0 += ks1; x1 += ks2 + 1u;
  TFR(17) TFR(29) TFR(16) TFR(24) x0 += ks2; x1 += ks0 + 2u;
  TFR(13) TFR(15) TFR(26) TFR(6)  x0 += ks0; x1 += ks1 + 3u;
  TFR(17) TFR(29) TFR(16) TFR(24) x0 += ks1; x1 += ks2 + 4u;
  TFR(13) TFR(15) TFR(26) TFR(6)  x0 += ks2; x1 += ks0 + 5u;
#undef TFR
  o0 = x0; o1 = x1;
}

__device__ __forceinline__ uint32_t random_bits_at(uint32_t idx) {
  uint32_t o0, o1; threefry2x32(0u, idx, o0, o1);   // counter = (hi,lo) of flat idx
  return o0 ^ o1;                                    // 32-bit partitionable combine
}

// Exact-value gumbel (OCML logf) -- the winner-deciding path, unchanged from R6.
__device__ __forceinline__ float gumbel_ocml(uint32_t mant) {
  float uni;
  if (mant == 0u) uni = 1.17549435e-38f;            // max(tiny, 0*(1-tiny)+tiny)
  else uni = __uint_as_float(0x3f800000u | mant) - 1.0f;  // exact
  float l1 = logf(uni);
  float n1 = -l1;
  float l2 = logf(n1);
  return -l2;
}

// ==================== categorical sampling: one WAVE per (t,h) task ====================
//
// Parallel-equivalent semantics: the sequential strict-> scan returns (max val, FIRST
// index attaining it). Lane l handles j = l + 64k (k increasing): per-lane strict->
// keeps the lane's first occurrence; the final butterfly takes (max val, min index on
// exact ties). Each j belongs to exactly one lane -> result identical to the scan.
//
// Screen: wave-uniform bits-domain threshold B from the R6-VERIFIED mstar formula
// (absmax=0 in R6), with T (wave-max of EXACT evals so far, <= task max) in place of M:
//   bits < B = mstar(T, Lmx)<<9  ==>  val_j <= T - 1e-3 + eps < T <= M_final
// so a skipped j can neither win nor tie (same inequality chain as R6; monotone
// floor-shift bits>=B <=> mant>=mstar; mstar <= 2^23-8 so B fits u32).
// Fast path per 64 positions: one threefry per lane + ONE v_cmp + wave-level vccz
// branch (no exec churn, no logit load, no transcendentals).
// Iteration 0 (B=0): all 64 lanes evaluate exact gumbel IN PARALLEL (efficient warm
// start; T immediately = max of 64 draws). Expected later body entries ~ H_24 ~ 4
// (record batches); each body ~90 wave-instrs, amortized over 1568 positions.

__global__ __launch_bounds__(512) void k_samp() {
  int lane  = threadIdx.x & 63;
  int wtask = blockIdx.x * 8 + (threadIdx.x >> 6);  // wave id == output task id, < NTASK2
  int t = wtask >> 1;               // (s,r) id
  int h = wtask & 1;                // half
  int b = (t & 2047) >> 6;
  const float* Lh = g_logits + b * 3136 + h * 1568;
  float Lmx = g_lmax[b];
  uint32_t vidx = (uint32_t)t * 3136u + (uint32_t)(h * 1568) + (uint32_t)lane;

  float bestV = -INFINITY; int bestJ = 0;           // bestJ relative to half start
  uint32_t B = 0u;                                  // bits-domain screen threshold

  // 24 full iterations: all 64 lanes active, jj = lane + 64k
  for (int k = 0; k < 24; ++k) {
    uint32_t bits = random_bits_at(vidx);
    if (__any(bits >= B)) {                         // wave-level; rare after iter 0
      int jj = lane + (k << 6);
      bool upd = false;
      if (bits >= B) {
        float val = Lh[jj] + gumbel_ocml(bits >> 9);
        if (val > bestV) { bestV = val; bestJ = jj; upd = true; }
      }
      if (__any(upd)) {                             // T improved -> tighten B
        float m = bestV;
        #pragma unroll
        for (int off = 32; off; off >>= 1) m = fmaxf(m, __shfl_xor(m, off));
        float Tp = m - Lmx - 1e-3f;                 // R6-verified margin
        uint32_t mthr = 0u;
        if (Tp > -80.0f) {                          // -inf/NaN safe
          float u_thr = expf(-expf(-Tp));
          int mi = (int)(u_thr * 8388608.0f) - 8;   // R6-verified -8 slack
          mthr = mi > 0 ? (uint32_t)mi : 0u;
        }
        B = mthr << 9;                              // mthr <= 2^23-8 -> fits u32
      }
    }
    vidx += 64u;
  }
  // tail half-iteration: jj = 1536 + lane, lanes < 32 only (1568 = 24*64 + 32)
  {
    uint32_t bits = random_bits_at(vidx);
    bool pass = (lane < 32) && (bits >= B);
    if (__any(pass)) {
      if (pass) {
        int jj = 1536 + lane;
        float val = Lh[jj] + gumbel_ocml(bits >> 9);
        if (val > bestV) { bestV = val; bestJ = jj; }
      }
    }
  }
  // final argmax reduce: max val, min index among exact ties
  #pragma unroll
  for (int off = 32; off; off >>= 1) {
    float ov = __shfl_xor(bestV, off);
    int   oj = __shfl_xor(bestJ, off);
    if (ov > bestV || (ov == bestV && oj < bestJ)) { bestV = ov; bestJ = oj; }
  }
  if (lane == 0) {
    g_pM[wtask] = bestV;
    g_pJ[wtask] = h * 1568 + bestJ;                 // absolute j within the row
  }
}

// ---------------- merge halves: strict > keeps first-occurrence argmax ----------------
__global__ __launch_bounds__(256) void k_merge(float* __restrict__ out) {
  int t = blockIdx.x * 256 + threadIdx.x;           // < NSAMP_T (2504*256 exactly)
  float M0 = g_pM[2 * t], M1 = g_pM[2 * t + 1];
  int j = (M1 > M0) ? g_pJ[2 * t + 1] : g_pJ[2 * t];
  int r = t & 2047;
  out[(size_t)r * 3136 + (size_t)j] = 0.0f;
}

// ---------------- launch ----------------
extern "C" void kernel_launch(void* const* d_in, const int* in_sizes, int n_in,
                              void* d_out, int out_size, void* d_ws, size_t ws_size,
                              hipStream_t stream) {
  (void)in_sizes; (void)n_in; (void)d_ws; (void)ws_size; (void)out_size;
  const float* x_old = (const float*)d_in[0];
  const float* x     = (const float*)d_in[1];
  float* out = (float*)d_out;

  k_rng  <<<1,     64, 0, stream>>>();
  k_dist <<<14112, 256, 0, stream>>>(x_old);
  k_mean1<<<NMEANB,256, 0, stream>>>();
  k_mean2<<<1,     64, 0, stream>>>();
  k_prob1<<<1568,  256, 0, stream>>>();
  k_pool <<<392,   256, 0, stream>>>();
  k_norm <<<1,     64, 0, stream>>>();
  k_copy <<<6272,  256, 0, stream>>>((const float4*)x, (float4*)out);
  k_samp <<<160256, 512, 0, stream>>>();            // one wave per (t,h) task
  k_merge<<<2504,  256, 0, stream>>>(out);
}

// Round 5
// 5729.641 us; speedup vs baseline: 1.0971x; 1.0971x over previous
//
#include <hip/hip_runtime.h>
#include <math.h>
#include <stdint.h>

// Replicate XLA numerics: no FMA contraction anywhere.
#pragma clang fp contract(off)

// ---------------- problem constants ----------------
// x_old: (32,3,224,224) f32; x/out: (32,64,56,56) f32
#define NDIST   3612672   // 32*9*112*112 = 882*4096
#define NPMAP   401408    // 32*112*112
#define NPOOL   100352    // 32*3136
#define NSAMP_T 641024    // 313 * 2048 (one task per (s,r))
#define NTASK2  1282048   // NSAMP_T * 2 half-row tasks
#define NMEANB  882       // k_mean1 blocks (4096 elems each)

__device__ __align__(16) float g_dist[NDIST];
__device__ __align__(16) float g_pmap[NPMAP];
__device__ __align__(16) float g_pooled[NPOOL];
__device__ __align__(16) float g_logits[NPOOL];
__device__ __align__(16) float g_pM[NTASK2];
__device__ __align__(16) int   g_pJ[NTASK2];
__device__ float g_partial[NMEANB];
__device__ float g_lmax[32];
__device__ float g_mean[1];
__device__ int   g_sij[18];

// ---------------- NumPy SeedSequence(0) + PCG64 + 32-bit buffered Lemire ----------------
// VERIFIED R6 (absmax=0): mix = x*L - y*R; low-half-first next32; Lemire-32 thr=4;
// initstate = (gs[0]<<64)|gs[1].
__device__ __forceinline__ uint32_t ss_hash(uint32_t value, uint32_t& hc) {
  value ^= hc; hc *= 0x931e8875u; value *= hc; value ^= value >> 16; return value;
}
__device__ __forceinline__ uint32_t ss_mix(uint32_t x, uint32_t y) {
  uint32_t r = x * 0xca01f9ddu - y * 0x4973f715u;   // multiply-SUBTRACT (numpy mix)
  r ^= r >> 16; return r;
}

__global__ void k_rng() {
  if (threadIdx.x != 0 || blockIdx.x != 0) return;
  uint32_t pool[4];
  uint32_t hc = 0x43b0d7e5u;                       // INIT_A
  for (int i = 0; i < 4; ++i) pool[i] = ss_hash(0u, hc);
  for (int is = 0; is < 4; ++is)
    for (int id = 0; id < 4; ++id)
      if (is != id) pool[id] = ss_mix(pool[id], ss_hash(pool[is], hc));
  uint32_t hb = 0x8b51f9ddu;                       // INIT_B
  uint32_t w[8];
  for (int i = 0; i < 8; ++i) {
    uint32_t dv = pool[i & 3];
    dv ^= hb; hb *= 0x58f38dedu; dv *= hb; dv ^= dv >> 16; w[i] = dv;
  }
  uint64_t gs[4];
  for (int i = 0; i < 4; ++i) gs[i] = (uint64_t)w[2*i] | ((uint64_t)w[2*i+1] << 32);
  const __uint128_t MUL = (((__uint128_t)0x2360ED051FC65DA4ull) << 64) | 0x4385DF649FCCF645ull;
  __uint128_t initstate = (((__uint128_t)gs[0]) << 64) | gs[1];
  __uint128_t initseq   = (((__uint128_t)gs[2]) << 64) | gs[3];
  __uint128_t inc   = (initseq << 1) | 1;
  __uint128_t state = 0;
  state = state * MUL + inc;
  state += initstate;
  state = state * MUL + inc;

  bool has32 = false; uint32_t saved32 = 0;
  auto next32 = [&]() -> uint32_t {
    if (has32) { has32 = false; return saved32; }
    state = state * MUL + inc;
    uint64_t xo = (uint64_t)(state >> 64) ^ (uint64_t)state;
    uint32_t rot = (uint32_t)(state >> 122) & 63u;
    uint64_t v = (xo >> rot) | (xo << ((64u - rot) & 63u));   // rotr
    has32 = true; saved32 = (uint32_t)(v >> 32);              // high half buffered
    return (uint32_t)v;                                       // low half first
  };

  for (int k = 0; k < 18; ++k) {
    uint64_t m = (uint64_t)next32() * 7ull;
    uint32_t leftover = (uint32_t)m;
    if (leftover < 7u) {
      while (leftover < 4u) { m = (uint64_t)next32() * 7ull; leftover = (uint32_t)m; }
    }
    g_sij[k] = (int)(uint32_t)(m >> 32) - 3;
  }
}

// ---------------- distance: per-patch squared-diff 7x7 stride-2 window sums ----------------
__global__ __launch_bounds__(256) void k_dist(const float* __restrict__ xold) {
  int idx = blockIdx.x * 256 + threadIdx.x;
  if (idx >= NDIST) return;
  int ox = idx % 112; int tt = idx / 112;
  int oy = tt % 112;  tt /= 112;
  int p = tt % 9;     int b = tt / 9;
  int si = g_sij[p], sj = g_sij[9 + p];
  const float* xb = xold + (size_t)b * 3 * 224 * 224;
  float acc = 0.f;
  for (int kh = 0; kh < 7; ++kh) {
    int hb = 2 * oy + kh - 3;
    int hs = hb + si;
    for (int kw = 0; kw < 7; ++kw) {
      int wb = 2 * ox + kw - 3;
      int wsf = wb + sj;
      float s = 0.f;
      for (int c = 0; c < 3; ++c) {
        const float* xc = xb + c * 224 * 224;
        float bv = (hb >= 0 && hb < 224 && wb >= 0 && wb < 224) ? xc[hb * 224 + wb] : 0.f;
        float sv = (hs >= 0 && hs < 224 && wsf >= 0 && wsf < 224) ? xc[hs * 224 + wsf] : 0.f;
        float d = bv - sv;
        s = s + d * d;              // channel sum, in order
      }
      acc = acc + s;                // window sum, row-major order
    }
  }
  g_dist[idx] = acc;
}

// ---------------- global mean: deterministic two-stage reduce ----------------
__global__ __launch_bounds__(256) void k_mean1() {
  __shared__ float red[256];
  int base = blockIdx.x * 4096;
  float acc = 0.f;
  #pragma unroll
  for (int i = 0; i < 4; ++i) {
    float4 v = *(const float4*)(g_dist + base + threadIdx.x * 4 + i * 1024);
    acc = acc + v.x + v.y + v.z + v.w;
  }
  red[threadIdx.x] = acc;
  __syncthreads();
  for (int s = 128; s > 0; s >>= 1) {
    if (threadIdx.x < s) red[threadIdx.x] += red[threadIdx.x + s];
    __syncthreads();
  }
  if (threadIdx.x == 0) g_partial[blockIdx.x] = red[0];
}
__global__ void k_mean2() {
  if (threadIdx.x != 0 || blockIdx.x != 0) return;
  float acc = 0.f;
  for (int i = 0; i < NMEANB; ++i) acc = acc + g_partial[i];
  g_mean[0] = acc / 3612672.0f;
}

// ---------------- pmap = ((sum_p exp(-d/m/2))/9)^2 ----------------
__global__ __launch_bounds__(256) void k_prob1() {
  int idx = blockIdx.x * 256 + threadIdx.x;
  if (idx >= NPMAP) return;
  int xy = idx % 12544; int b = idx / 12544;
  float m = g_mean[0];
  float ssum = 0.f;
  for (int p = 0; p < 9; ++p) {
    float d = g_dist[(size_t)(b * 9 + p) * 12544 + xy];
    float t = (-d / m) / 2.0f;                      // / BW^2 == /1.0 exact
    float e = expf(t);
    ssum = ssum + e;
  }
  float q = ssum / 9.0f;
  g_pmap[idx] = q * q;                              // ** (1/TEMP) == ^2
}

// ---------------- min-pool 3x3 stride 2 pad 1 ----------------
__global__ __launch_bounds__(256) void k_pool() {
  int idx = blockIdx.x * 256 + threadIdx.x;
  if (idx >= NPOOL) return;
  int ox = idx % 56; int tt = idx / 56;
  int oy = tt % 56;  int b = tt / 56;
  float mn = INFINITY;
  for (int kh = 0; kh < 3; ++kh) {
    int y = 2 * oy - 1 + kh; if (y < 0 || y >= 112) continue;
    for (int kw = 0; kw < 3; ++kw) {
      int x = 2 * ox - 1 + kw; if (x < 0 || x >= 112) continue;
      mn = fminf(mn, g_pmap[(size_t)(b * 112 + y) * 112 + x]);
    }
  }
  g_pooled[idx] = mn;
}

// ---------------- per-b row sum, logits = logf(p/S + 1e-8), row max ----------------
__global__ void k_norm() {
  int b = threadIdx.x;
  if (b >= 32 || blockIdx.x != 0) return;
  const float* P = g_pooled + b * 3136;
  float s = 0.f;
  for (int i = 0; i < 3136; ++i) s = s + P[i];
  float lm = -INFINITY;
  for (int i = 0; i < 3136; ++i) {
    float fl = P[i] / s;
    float lg = logf(fl + 1e-8f);
    g_logits[b * 3136 + i] = lg;
    lm = fmaxf(lm, lg);
  }
  g_lmax[b] = lm;
}

// ---------------- out = x ----------------
__global__ __launch_bounds__(256) void k_copy(const float4* __restrict__ x, float4* __restrict__ out) {
  int i = blockIdx.x * 256 + threadIdx.x;           // 1,605,632 float4 exactly
  out[i] = x[i];
}

// ---------------- JAX threefry2x32, key = (0, 42), partitionable 32-bit bits ----------------
__device__ __forceinline__ uint32_t rotl32(uint32_t x, int r) { return __builtin_rotateleft32(x, r); }
__device__ __forceinline__ void threefry2x32(uint32_t x0, uint32_t x1, uint32_t& o0, uint32_t& o1) {
  const uint32_t ks0 = 0u, ks1 = 42u, ks2 = 0x1BD11BDAu ^ 0u ^ 42u;
  x0 += ks0; x1 += ks1;
#define TFR(r) { x0 += x1; x1 = rotl32(x1, (r)); x1 ^= x0; }
  TFR(13) TFR(15) TFR(26) TFR(6)  x0 += ks1; x1 += ks2 + 1u;
  TFR(17) TFR(29) TFR(16) TFR(24) x0 += ks2; x1 += ks0 + 2u;
  TFR(13) TFR(15) TFR(26) TFR(6)  x0 += ks0; x1 += ks1 + 3u;
  TFR(17) TFR(29) TFR(16) TFR(24) x0 += ks1; x1 += ks2 + 4u;
  TFR(13) TFR(15) TFR(26) TFR(6)  x0 += ks2; x1 += ks0 + 5u;
#undef TFR
  o0 = x0; o1 = x1;
}

__device__ __forceinline__ uint32_t random_bits_at(uint32_t idx) {
  uint32_t o0, o1; threefry2x32(0u, idx, o0, o1);   // counter = (hi,lo) of flat idx
  return o0 ^ o1;                                    // 32-bit partitionable combine
}

// Exact-value gumbel (OCML logf) -- the winner-deciding path, unchanged from R6.
__device__ __forceinline__ float gumbel_ocml(uint32_t mant) {
  float uni;
  if (mant == 0u) uni = 1.17549435e-38f;            // max(tiny, 0*(1-tiny)+tiny)
  else uni = __uint_as_float(0x3f800000u | mant) - 1.0f;  // exact
  float l1 = logf(uni);
  float n1 = -l1;
  float l2 = logf(n1);
  return -l2;
}

// ==================== categorical sampling: branch-free top-2 scan + one exact pass ====================
//
// One WAVE per (t,h) task; lane l handles j = l + 64k. Parallel semantics == sequential
// strict-> scan: per-lane j increasing + final (max val, min index on exact ties) butterfly.
//
// Phase 1 (branch-free, fixed length, no loads/transcendentals/exec-churn): per lane,
// track b1 = max bits, j1 = FIRST index attaining b1 (strict > keeps earliest), and
// b2 = 2nd-max bits (value only). Update: gt1 = x > b1; j1 = gt1 ? j : j1;
// b2 = max(min(x, b1_old), b2); b1 = max(b1, x).   (5 VALU + threefry per position)
//
// Phase 2 (once per task):
//  * val1 = L[j1] + gumbel_ocml(b1>>9) for ALL 64 lanes in parallel -- exact values of
//    real positions, so T0 = wave_max(val1) <= M_final.
//  * B0 = mstar(T0, Lmx) << 9 via the R6-VERIFIED margin formula: bits < B0 ==>
//    val <= T0 - 1e-3 + eps < T0 <= M_final -- skipped positions can neither win nor
//    tie the final max. (bits >= B0 <=> mant >= mstar: floor-shift monotone.)
//  * candidate set: lanes with b1 >= B0 contribute (val1, j1). A lane could hold MORE
//    candidates only if its 2nd-max b2 >= B0 -> that lane rescans its 25 positions
//    exactly (exec-masked; expected ~5% of waves). B0 == 0 -> all lanes rescan (never
//    in practice; sound fallback).
//  * butterfly (max val, min j on exact ties) == first-occurrence argmax of the row.

__global__ __launch_bounds__(512) void k_samp() {
  int lane  = threadIdx.x & 63;
  int wtask = blockIdx.x * 8 + (threadIdx.x >> 6);  // wave id == output task id, < NTASK2
  int t = wtask >> 1;               // (s,r) id
  int h = wtask & 1;                // half
  int b = (t & 2047) >> 6;
  const float* Lh = g_logits + b * 3136 + h * 1568;
  float Lmx = g_lmax[b];
  uint32_t vbase = (uint32_t)t * 3136u + (uint32_t)(h * 1568);

  // ---- phase 1: branch-free top-2 bits scan (jj = lane + 64k) ----
  uint32_t b1, b2 = 0u; int j1;
  {
    uint32_t x = random_bits_at(vbase + (uint32_t)lane);
    b1 = x; j1 = lane;              // k = 0 unconditionally seeds (b1, j1)
  }
  uint32_t vidx = vbase + (uint32_t)lane + 64u;
  for (int k = 1; k < 24; ++k) {
    uint32_t x = random_bits_at(vidx);
    int jj = lane + (k << 6);
    bool gt1 = x > b1;              // strict: equal bits keep earlier j
    j1 = gt1 ? jj : j1;
    b2 = max(min(x, b1), b2);       // 2nd max (uses OLD b1)
    b1 = max(b1, x);
    vidx += 64u;
  }
  if (lane < 32) {                  // tail: 1568 = 24*64 + 32, jj = 1536 + lane
    uint32_t x = random_bits_at(vidx);
    int jj = 1536 + lane;
    bool gt1 = x > b1;
    j1 = gt1 ? jj : j1;
    b2 = max(min(x, b1), b2);
    b1 = max(b1, x);
  }

  // ---- phase 2: one exact vector pass + sound cutoff ----
  float val1 = Lh[j1] + gumbel_ocml(b1 >> 9);       // exact val of a real position
  float T0 = val1;
  #pragma unroll
  for (int off = 32; off; off >>= 1) T0 = fmaxf(T0, __shfl_xor(T0, off));

  float Tp = T0 - Lmx - 1e-3f;                      // R6-verified margin
  uint32_t mthr = 0u;
  if (Tp > -80.0f) {                                // -inf/NaN safe
    float u_thr = expf(-expf(-Tp));
    int mi = (int)(u_thr * 8388608.0f) - 8;         // R6-verified -8 slack
    mthr = mi > 0 ? (uint32_t)mi : 0u;
  }
  uint32_t B0 = mthr << 9;                          // bits-domain cutoff

  float bestV; int bestJ;
  if (b1 >= B0) { bestV = val1; bestJ = j1; }
  else          { bestV = -INFINITY; bestJ = 0x7fffffff; }

  bool flag = (b2 >= B0) || (B0 == 0u);             // lane may hold a 2nd+ candidate
  if (__any(flag)) {
    if (flag) {
      uint32_t vi = vbase + (uint32_t)lane;
      for (int k = 0; k < 25; ++k) {
        if (k == 24 && lane >= 32) break;
        uint32_t x = random_bits_at(vi);
        if (x >= B0) {
          int jj = lane + (k << 6);
          float v = Lh[jj] + gumbel_ocml(x >> 9);
          if (v > bestV || (v == bestV && jj < bestJ)) { bestV = v; bestJ = jj; }
        }
        vi += 64u;
      }
    }
  }

  // ---- wave argmax: max val, min index among exact ties ----
  #pragma unroll
  for (int off = 32; off; off >>= 1) {
    float ov = __shfl_xor(bestV, off);
    int   oj = __shfl_xor(bestJ, off);
    if (ov > bestV || (ov == bestV && oj < bestJ)) { bestV = ov; bestJ = oj; }
  }
  if (lane == 0) {
    g_pM[wtask] = bestV;
    g_pJ[wtask] = h * 1568 + bestJ;                 // absolute j within the row
  }
}

// ---------------- merge halves: strict > keeps first-occurrence argmax ----------------
__global__ __launch_bounds__(256) void k_merge(float* __restrict__ out) {
  int t = blockIdx.x * 256 + threadIdx.x;           // < NSAMP_T (2504*256 exactly)
  float M0 = g_pM[2 * t], M1 = g_pM[2 * t + 1];
  int j = (M1 > M0) ? g_pJ[2 * t + 1] : g_pJ[2 * t];
  int r = t & 2047;
  out[(size_t)r * 3136 + (size_t)j] = 0.0f;
}

// ---------------- launch ----------------
extern "C" void kernel_launch(void* const* d_in, const int* in_sizes, int n_in,
                              void* d_out, int out_size, void* d_ws, size_t ws_size,
                              hipStream_t stream) {
  (void)in_sizes; (void)n_in; (void)d_ws; (void)ws_size; (void)out_size;
  const float* x_old = (const float*)d_in[0];
  const float* x     = (const float*)d_in[1];
  float* out = (float*)d_out;

  k_rng  <<<1,     64, 0, stream>>>();
  k_dist <<<14112, 256, 0, stream>>>(x_old);
  k_mean1<<<NMEANB,256, 0, stream>>>();
  k_mean2<<<1,     64, 0, stream>>>();
  k_prob1<<<1568,  256, 0, stream>>>();
  k_pool <<<392,   256, 0, stream>>>();
  k_norm <<<1,     64, 0, stream>>>();
  k_copy <<<6272,  256, 0, stream>>>((const float4*)x, (float4*)out);
  k_samp <<<160256, 512, 0, stream>>>();            // one wave per (t,h) task
  k_merge<<<2504,  256, 0, stream>>>(out);
}

// Round 6
// 4959.855 us; speedup vs baseline: 1.2673x; 1.1552x over previous
//
#include <hip/hip_runtime.h>
#include <math.h>
#include <stdint.h>

// Replicate XLA numerics: no FMA contraction anywhere.
#pragma clang fp contract(off)

// ---------------- problem constants ----------------
// x_old: (32,3,224,224) f32; x/out: (32,64,56,56) f32
#define NDIST   3612672   // 32*9*112*112 = 882*4096
#define NPMAP   401408    // 32*112*112
#define NPOOL   100352    // 32*3136
#define NSAMP_T 641024    // 313 * 2048 (one task per (s,r))
#define NTASK2  1282048   // NSAMP_T * 2 half-row tasks
#define NMEANB  882       // k_mean1 blocks (4096 elems each)

__device__ __align__(16) float g_dist[NDIST];
__device__ __align__(16) float g_pmap[NPMAP];
__device__ __align__(16) float g_pooled[NPOOL];
__device__ __align__(16) float g_logits[NPOOL];
__device__ __align__(16) float g_pM[NTASK2];
__device__ __align__(16) int   g_pJ[NTASK2];
__device__ float g_partial[NMEANB];
__device__ float g_lmax[32];
__device__ float g_mean[1];
__device__ int   g_sij[18];

// ---------------- NumPy SeedSequence(0) + PCG64 + 32-bit buffered Lemire ----------------
// VERIFIED R6 (absmax=0): mix = x*L - y*R; low-half-first next32; Lemire-32 thr=4;
// initstate = (gs[0]<<64)|gs[1].
__device__ __forceinline__ uint32_t ss_hash(uint32_t value, uint32_t& hc) {
  value ^= hc; hc *= 0x931e8875u; value *= hc; value ^= value >> 16; return value;
}
__device__ __forceinline__ uint32_t ss_mix(uint32_t x, uint32_t y) {
  uint32_t r = x * 0xca01f9ddu - y * 0x4973f715u;   // multiply-SUBTRACT (numpy mix)
  r ^= r >> 16; return r;
}

__global__ void k_rng() {
  if (threadIdx.x != 0 || blockIdx.x != 0) return;
  uint32_t pool[4];
  uint32_t hc = 0x43b0d7e5u;                       // INIT_A
  for (int i = 0; i < 4; ++i) pool[i] = ss_hash(0u, hc);
  for (int is = 0; is < 4; ++is)
    for (int id = 0; id < 4; ++id)
      if (is != id) pool[id] = ss_mix(pool[id], ss_hash(pool[is], hc));
  uint32_t hb = 0x8b51f9ddu;                       // INIT_B
  uint32_t w[8];
  for (int i = 0; i < 8; ++i) {
    uint32_t dv = pool[i & 3];
    dv ^= hb; hb *= 0x58f38dedu; dv *= hb; dv ^= dv >> 16; w[i] = dv;
  }
  uint64_t gs[4];
  for (int i = 0; i < 4; ++i) gs[i] = (uint64_t)w[2*i] | ((uint64_t)w[2*i+1] << 32);
  const __uint128_t MUL = (((__uint128_t)0x2360ED051FC65DA4ull) << 64) | 0x4385DF649FCCF645ull;
  __uint128_t initstate = (((__uint128_t)gs[0]) << 64) | gs[1];
  __uint128_t initseq   = (((__uint128_t)gs[2]) << 64) | gs[3];
  __uint128_t inc   = (initseq << 1) | 1;
  __uint128_t state = 0;
  state = state * MUL + inc;
  state += initstate;
  state = state * MUL + inc;

  bool has32 = false; uint32_t saved32 = 0;
  auto next32 = [&]() -> uint32_t {
    if (has32) { has32 = false; return saved32; }
    state = state * MUL + inc;
    uint64_t xo = (uint64_t)(state >> 64) ^ (uint64_t)state;
    uint32_t rot = (uint32_t)(state >> 122) & 63u;
    uint64_t v = (xo >> rot) | (xo << ((64u - rot) & 63u));   // rotr
    has32 = true; saved32 = (uint32_t)(v >> 32);              // high half buffered
    return (uint32_t)v;                                       // low half first
  };

  for (int k = 0; k < 18; ++k) {
    uint64_t m = (uint64_t)next32() * 7ull;
    uint32_t leftover = (uint32_t)m;
    if (leftover < 7u) {
      while (leftover < 4u) { m = (uint64_t)next32() * 7ull; leftover = (uint32_t)m; }
    }
    g_sij[k] = (int)(uint32_t)(m >> 32) - 3;
  }
}

// ---------------- distance: per-patch squared-diff 7x7 stride-2 window sums ----------------
__global__ __launch_bounds__(256) void k_dist(const float* __restrict__ xold) {
  int idx = blockIdx.x * 256 + threadIdx.x;
  if (idx >= NDIST) return;
  int ox = idx % 112; int tt = idx / 112;
  int oy = tt % 112;  tt /= 112;
  int p = tt % 9;     int b = tt / 9;
  int si = g_sij[p], sj = g_sij[9 + p];
  const float* xb = xold + (size_t)b * 3 * 224 * 224;
  float acc = 0.f;
  for (int kh = 0; kh < 7; ++kh) {
    int hb = 2 * oy + kh - 3;
    int hs = hb + si;
    for (int kw = 0; kw < 7; ++kw) {
      int wb = 2 * ox + kw - 3;
      int wsf = wb + sj;
      float s = 0.f;
      for (int c = 0; c < 3; ++c) {
        const float* xc = xb + c * 224 * 224;
        float bv = (hb >= 0 && hb < 224 && wb >= 0 && wb < 224) ? xc[hb * 224 + wb] : 0.f;
        float sv = (hs >= 0 && hs < 224 && wsf >= 0 && wsf < 224) ? xc[hs * 224 + wsf] : 0.f;
        float d = bv - sv;
        s = s + d * d;              // channel sum, in order
      }
      acc = acc + s;                // window sum, row-major order
    }
  }
  g_dist[idx] = acc;
}

// ---------------- global mean: deterministic two-stage reduce ----------------
__global__ __launch_bounds__(256) void k_mean1() {
  __shared__ float red[256];
  int base = blockIdx.x * 4096;
  float acc = 0.f;
  #pragma unroll
  for (int i = 0; i < 4; ++i) {
    float4 v = *(const float4*)(g_dist + base + threadIdx.x * 4 + i * 1024);
    acc = acc + v.x + v.y + v.z + v.w;
  }
  red[threadIdx.x] = acc;
  __syncthreads();
  for (int s = 128; s > 0; s >>= 1) {
    if (threadIdx.x < s) red[threadIdx.x] += red[threadIdx.x + s];
    __syncthreads();
  }
  if (threadIdx.x == 0) g_partial[blockIdx.x] = red[0];
}
__global__ void k_mean2() {
  if (threadIdx.x != 0 || blockIdx.x != 0) return;
  float acc = 0.f;
  for (int i = 0; i < NMEANB; ++i) acc = acc + g_partial[i];
  g_mean[0] = acc / 3612672.0f;
}

// ---------------- pmap = ((sum_p exp(-d/m/2))/9)^2 ----------------
__global__ __launch_bounds__(256) void k_prob1() {
  int idx = blockIdx.x * 256 + threadIdx.x;
  if (idx >= NPMAP) return;
  int xy = idx % 12544; int b = idx / 12544;
  float m = g_mean[0];
  float ssum = 0.f;
  for (int p = 0; p < 9; ++p) {
    float d = g_dist[(size_t)(b * 9 + p) * 12544 + xy];
    float t = (-d / m) / 2.0f;                      // / BW^2 == /1.0 exact
    float e = expf(t);
    ssum = ssum + e;
  }
  float q = ssum / 9.0f;
  g_pmap[idx] = q * q;                              // ** (1/TEMP) == ^2
}

// ---------------- min-pool 3x3 stride 2 pad 1 ----------------
__global__ __launch_bounds__(256) void k_pool() {
  int idx = blockIdx.x * 256 + threadIdx.x;
  if (idx >= NPOOL) return;
  int ox = idx % 56; int tt = idx / 56;
  int oy = tt % 56;  int b = tt / 56;
  float mn = INFINITY;
  for (int kh = 0; kh < 3; ++kh) {
    int y = 2 * oy - 1 + kh; if (y < 0 || y >= 112) continue;
    for (int kw = 0; kw < 3; ++kw) {
      int x = 2 * ox - 1 + kw; if (x < 0 || x >= 112) continue;
      mn = fminf(mn, g_pmap[(size_t)(b * 112 + y) * 112 + x]);
    }
  }
  g_pooled[idx] = mn;
}

// ---------------- per-b row sum, logits = logf(p/S + 1e-8), row max ----------------
__global__ void k_norm() {
  int b = threadIdx.x;
  if (b >= 32 || blockIdx.x != 0) return;
  const float* P = g_pooled + b * 3136;
  float s = 0.f;
  for (int i = 0; i < 3136; ++i) s = s + P[i];
  float lm = -INFINITY;
  for (int i = 0; i < 3136; ++i) {
    float fl = P[i] / s;
    float lg = logf(fl + 1e-8f);
    g_logits[b * 3136 + i] = lg;
    lm = fmaxf(lm, lg);
  }
  g_lmax[b] = lm;
}

// ---------------- out = x ----------------
__global__ __launch_bounds__(256) void k_copy(const float4* __restrict__ x, float4* __restrict__ out) {
  int i = blockIdx.x * 256 + threadIdx.x;           // 1,605,632 float4 exactly
  out[i] = x[i];
}

// ---------------- JAX threefry2x32, key = (0, 42), partitionable 32-bit bits ----------------
__device__ __forceinline__ uint32_t rotl32(uint32_t x, int r) { return __builtin_rotateleft32(x, r); }
__device__ __forceinline__ void threefry2x32(uint32_t x0, uint32_t x1, uint32_t& o0, uint32_t& o1) {
  const uint32_t ks0 = 0u, ks1 = 42u, ks2 = 0x1BD11BDAu ^ 0u ^ 42u;
  x0 += ks0; x1 += ks1;
#define TFR(r) { x0 += x1; x1 = rotl32(x1, (r)); x1 ^= x0; }
  TFR(13) TFR(15) TFR(26) TFR(6)  x0 += ks1; x1 += ks2 + 1u;
  TFR(17) TFR(29) TFR(16) TFR(24) x0 += ks2; x1 += ks0 + 2u;
  TFR(13) TFR(15) TFR(26) TFR(6)  x0 += ks0; x1 += ks1 + 3u;
  TFR(17) TFR(29) TFR(16) TFR(24) x0 += ks1; x1 += ks2 + 4u;
  TFR(13) TFR(15) TFR(26) TFR(6)  x0 += ks2; x1 += ks0 + 5u;
#undef TFR
  o0 = x0; o1 = x1;
}

__device__ __forceinline__ uint32_t random_bits_at(uint32_t idx) {
  uint32_t o0, o1; threefry2x32(0u, idx, o0, o1);   // counter = (hi,lo) of flat idx
  return o0 ^ o1;                                    // 32-bit partitionable combine
}

// ---- dual threefry, inline-asm, instruction-interleaved (exactly 140 VALU for 2 streams) ----
// Bit-exact vs threefry2x32 above: rotl(x,r) == v_alignbit_b32(x,x,32-r);
// ks0=0, ks1=42, ks2=0x1BD11BF0 (=0x1BD11BDA^42); injections folded to literals;
// the x0+=ks0 injection (+0) after round 12 is elided. Adjacent instrs are independent
// (A/B alternate) -> dependent ops are >=2 instrs apart (>=4 cyc at 2cyc issue):
// chain latency hidden WITHIN one wave regardless of occupancy.
#define TF_R(S) \
  "v_add_u32 %0, %0, %1\n\t" \
  "v_add_u32 %2, %2, %3\n\t" \
  "v_alignbit_b32 %1, %1, %1, " S "\n\t" \
  "v_alignbit_b32 %3, %3, %3, " S "\n\t" \
  "v_xor_b32 %1, %1, %0\n\t" \
  "v_xor_b32 %3, %3, %2\n\t"
#define TF_GX TF_R("19") TF_R("17") TF_R("6") TF_R("26")
#define TF_GY TF_R("15") TF_R("3") TF_R("16") TF_R("8")

__device__ __forceinline__ void tf2_dual(uint32_t inA, uint32_t inB,
                                         uint32_t& outA, uint32_t& outB) {
  uint32_t a0 = 0u, a1 = inA + 42u;                 // x0 += ks0(0), x1 += ks1(42)
  uint32_t b0 = 0u, b1 = inB + 42u;
  asm(TF_GX
      "v_add_u32 %0, 42, %0\n\t"
      "v_add_u32 %2, 42, %2\n\t"
      "v_add_u32 %1, 0x1bd11bf1, %1\n\t"            // ks2+1
      "v_add_u32 %3, 0x1bd11bf1, %3\n\t"
      TF_GY
      "v_add_u32 %0, 0x1bd11bf0, %0\n\t"            // ks2
      "v_add_u32 %2, 0x1bd11bf0, %2\n\t"
      "v_add_u32 %1, 2, %1\n\t"                     // ks0+2
      "v_add_u32 %3, 2, %3\n\t"
      TF_GX
      "v_add_u32 %1, 45, %1\n\t"                    // ks1+3 (x0+=ks0 elided)
      "v_add_u32 %3, 45, %3\n\t"
      TF_GY
      "v_add_u32 %0, 42, %0\n\t"
      "v_add_u32 %2, 42, %2\n\t"
      "v_add_u32 %1, 0x1bd11bf4, %1\n\t"            // ks2+4
      "v_add_u32 %3, 0x1bd11bf4, %3\n\t"
      TF_GX
      "v_add_u32 %0, 0x1bd11bf0, %0\n\t"            // ks2
      "v_add_u32 %2, 0x1bd11bf0, %2\n\t"
      "v_add_u32 %1, 5, %1\n\t"                     // ks0+5
      "v_add_u32 %3, 5, %3\n\t"
      "v_xor_b32 %0, %0, %1\n\t"                    // o0 ^ o1
      "v_xor_b32 %2, %2, %3"
      : "+v"(a0), "+v"(a1), "+v"(b0), "+v"(b1));
  outA = a0; outB = b0;
}

// Exact-value gumbel (OCML logf) -- the winner-deciding path, unchanged from R6.
__device__ __forceinline__ float gumbel_ocml(uint32_t mant) {
  float uni;
  if (mant == 0u) uni = 1.17549435e-38f;            // max(tiny, 0*(1-tiny)+tiny)
  else uni = __uint_as_float(0x3f800000u | mant) - 1.0f;  // exact
  float l1 = logf(uni);
  float n1 = -l1;
  float l2 = logf(n1);
  return -l2;
}

// ==================== categorical sampling: asm dual-threefry top-2 scan + one exact pass ====================
//
// Structure verified R5 (absmax=0): one WAVE per (t,h); lane l owns {j : j==l mod 64}
// in increasing order; final butterfly takes (max val, min index on exact ties) ==
// sequential first-occurrence argmax. Phase 2 (exact pass + R6-verified mstar cutoff +
// rare rescan) byte-identical to R5.
// Phase 1 now: 12 dual-chain asm iterations (jA=l+128k, jB=jA+64 -- same per-lane
// increasing order) + 32-lane tail. Exactly-counted inner loop kills the codegen
// hypothesis; instruction-interleaved chains kill the latency hypothesis.

#define TOP2_UPD(x, jj) { \
  bool g = (x) > w1; \
  j1 = g ? (jj) : j1; \
  w2 = max(min((x), w1), w2); \
  w1 = max(w1, (x)); }

__global__ __launch_bounds__(512) void k_samp() {
  int lane  = threadIdx.x & 63;
  int wtask = blockIdx.x * 8 + (threadIdx.x >> 6);  // wave id == output task id, < NTASK2
  int t = wtask >> 1;               // (s,r) id
  int h = wtask & 1;                // half
  int b = (t & 2047) >> 6;
  const float* Lh = g_logits + b * 3136 + h * 1568;
  float Lmx = g_lmax[b];
  uint32_t vbase = (uint32_t)t * 3136u + (uint32_t)(h * 1568);

  // ---- phase 1: dual-chain top-2 bits scan ----
  uint32_t w1, w2 = 0u; int j1;
  uint32_t vidx = vbase + (uint32_t)lane;
  {
    uint32_t xA, xB;
    tf2_dual(vidx, vidx + 64u, xA, xB);
    w1 = xA; j1 = lane;                             // jA = lane seeds
    TOP2_UPD(xB, lane + 64)
    vidx += 128u;
  }
  for (int k = 1; k < 12; ++k) {
    uint32_t xA, xB;
    tf2_dual(vidx, vidx + 64u, xA, xB);
    int jA = lane + (k << 7);
    TOP2_UPD(xA, jA)
    TOP2_UPD(xB, jA + 64)
    vidx += 128u;
  }
  if (lane < 32) {                  // tail: 1568 = 12*128 + 32, jj = 1536 + lane
    uint32_t x = random_bits_at(vbase + 1536u + (uint32_t)lane);
    TOP2_UPD(x, 1536 + lane)
  }

  // ---- phase 2: one exact vector pass + sound cutoff (R5-verified) ----
  float val1 = Lh[j1] + gumbel_ocml(w1 >> 9);       // exact val of a real position
  float T0 = val1;
  #pragma unroll
  for (int off = 32; off; off >>= 1) T0 = fmaxf(T0, __shfl_xor(T0, off));

  float Tp = T0 - Lmx - 1e-3f;                      // R6-verified margin
  uint32_t mthr = 0u;
  if (Tp > -80.0f) {                                // -inf/NaN safe
    float u_thr = expf(-expf(-Tp));
    int mi = (int)(u_thr * 8388608.0f) - 8;         // R6-verified -8 slack
    mthr = mi > 0 ? (uint32_t)mi : 0u;
  }
  uint32_t B0 = mthr << 9;                          // bits-domain cutoff

  float bestV; int bestJ;
  if (w1 >= B0) { bestV = val1; bestJ = j1; }
  else          { bestV = -INFINITY; bestJ = 0x7fffffff; }

  bool flag = (w2 >= B0) || (B0 == 0u);             // lane may hold a 2nd+ candidate
  if (__any(flag)) {
    if (flag) {
      uint32_t vi = vbase + (uint32_t)lane;
      for (int k = 0; k < 25; ++k) {
        if (k == 24 && lane >= 32) break;
        uint32_t x = random_bits_at(vi);
        if (x >= B0) {
          int jj = lane + (k << 6);
          float v = Lh[jj] + gumbel_ocml(x >> 9);
          if (v > bestV || (v == bestV && jj < bestJ)) { bestV = v; bestJ = jj; }
        }
        vi += 64u;
      }
    }
  }

  // ---- wave argmax: max val, min index among exact ties ----
  #pragma unroll
  for (int off = 32; off; off >>= 1) {
    float ov = __shfl_xor(bestV, off);
    int   oj = __shfl_xor(bestJ, off);
    if (ov > bestV || (ov == bestV && oj < bestJ)) { bestV = ov; bestJ = oj; }
  }
  if (lane == 0) {
    g_pM[wtask] = bestV;
    g_pJ[wtask] = h * 1568 + bestJ;                 // absolute j within the row
  }
}

// ---------------- merge halves: strict > keeps first-occurrence argmax ----------------
__global__ __launch_bounds__(256) void k_merge(float* __restrict__ out) {
  int t = blockIdx.x * 256 + threadIdx.x;           // < NSAMP_T (2504*256 exactly)
  float M0 = g_pM[2 * t], M1 = g_pM[2 * t + 1];
  int j = (M1 > M0) ? g_pJ[2 * t + 1] : g_pJ[2 * t];
  int r = t & 2047;
  out[(size_t)r * 3136 + (size_t)j] = 0.0f;
}

// ---------------- launch ----------------
extern "C" void kernel_launch(void* const* d_in, const int* in_sizes, int n_in,
                              void* d_out, int out_size, void* d_ws, size_t ws_size,
                              hipStream_t stream) {
  (void)in_sizes; (void)n_in; (void)d_ws; (void)ws_size; (void)out_size;
  const float* x_old = (const float*)d_in[0];
  const float* x     = (const float*)d_in[1];
  float* out = (float*)d_out;

  k_rng  <<<1,     64, 0, stream>>>();
  k_dist <<<14112, 256, 0, stream>>>(x_old);
  k_mean1<<<NMEANB,256, 0, stream>>>();
  k_mean2<<<1,     64, 0, stream>>>();
  k_prob1<<<1568,  256, 0, stream>>>();
  k_pool <<<392,   256, 0, stream>>>();
  k_norm <<<1,     64, 0, stream>>>();
  k_copy <<<6272,  256, 0, stream>>>((const float4*)x, (float4*)out);
  k_samp <<<160256, 512, 0, stream>>>();            // one wave per (t,h) task
  k_merge<<<2504,  256, 0, stream>>>(out);
}

// Round 7
// 4682.800 us; speedup vs baseline: 1.3423x; 1.0592x over previous
//
#include <hip/hip_runtime.h>
#include <math.h>
#include <stdint.h>

// Replicate XLA numerics: no FMA contraction anywhere.
#pragma clang fp contract(off)

// ---------------- problem constants ----------------
// x_old: (32,3,224,224) f32; x/out: (32,64,56,56) f32
#define NDIST   3612672   // 32*9*112*112 = 882*4096
#define NPMAP   401408    // 32*112*112
#define NPOOL   100352    // 32*3136
#define NSAMP_T 641024    // 313 * 2048 (one task per (s,r))
#define NTASK2  1282048   // NSAMP_T * 2 half-row tasks
#define NMEANB  882       // k_mean1 blocks (4096 elems each)

__device__ __align__(16) float g_dist[NDIST];
__device__ __align__(16) float g_pmap[NPMAP];
__device__ __align__(16) float g_pooled[NPOOL];
__device__ __align__(16) float g_logits[NPOOL];
__device__ __align__(16) float g_pM[NTASK2];
__device__ __align__(16) int   g_pJ[NTASK2];
__device__ float g_partial[NMEANB];
__device__ float g_rowsum[32];
__device__ float g_lmax[32];
__device__ float g_mean[1];
__device__ int   g_sij[18];

// ---------------- NumPy SeedSequence(0) + PCG64 + 32-bit buffered Lemire ----------------
// VERIFIED R6 (absmax=0): mix = x*L - y*R; low-half-first next32; Lemire-32 thr=4;
// initstate = (gs[0]<<64)|gs[1].
__device__ __forceinline__ uint32_t ss_hash(uint32_t value, uint32_t& hc) {
  value ^= hc; hc *= 0x931e8875u; value *= hc; value ^= value >> 16; return value;
}
__device__ __forceinline__ uint32_t ss_mix(uint32_t x, uint32_t y) {
  uint32_t r = x * 0xca01f9ddu - y * 0x4973f715u;   // multiply-SUBTRACT (numpy mix)
  r ^= r >> 16; return r;
}

__global__ void k_rng() {
  if (threadIdx.x != 0 || blockIdx.x != 0) return;
  uint32_t pool[4];
  uint32_t hc = 0x43b0d7e5u;                       // INIT_A
  for (int i = 0; i < 4; ++i) pool[i] = ss_hash(0u, hc);
  for (int is = 0; is < 4; ++is)
    for (int id = 0; id < 4; ++id)
      if (is != id) pool[id] = ss_mix(pool[id], ss_hash(pool[is], hc));
  uint32_t hb = 0x8b51f9ddu;                       // INIT_B
  uint32_t w[8];
  for (int i = 0; i < 8; ++i) {
    uint32_t dv = pool[i & 3];
    dv ^= hb; hb *= 0x58f38dedu; dv *= hb; dv ^= dv >> 16; w[i] = dv;
  }
  uint64_t gs[4];
  for (int i = 0; i < 4; ++i) gs[i] = (uint64_t)w[2*i] | ((uint64_t)w[2*i+1] << 32);
  const __uint128_t MUL = (((__uint128_t)0x2360ED051FC65DA4ull) << 64) | 0x4385DF649FCCF645ull;
  __uint128_t initstate = (((__uint128_t)gs[0]) << 64) | gs[1];
  __uint128_t initseq   = (((__uint128_t)gs[2]) << 64) | gs[3];
  __uint128_t inc   = (initseq << 1) | 1;
  __uint128_t state = 0;
  state = state * MUL + inc;
  state += initstate;
  state = state * MUL + inc;

  bool has32 = false; uint32_t saved32 = 0;
  auto next32 = [&]() -> uint32_t {
    if (has32) { has32 = false; return saved32; }
    state = state * MUL + inc;
    uint64_t xo = (uint64_t)(state >> 64) ^ (uint64_t)state;
    uint32_t rot = (uint32_t)(state >> 122) & 63u;
    uint64_t v = (xo >> rot) | (xo << ((64u - rot) & 63u));   // rotr
    has32 = true; saved32 = (uint32_t)(v >> 32);              // high half buffered
    return (uint32_t)v;                                       // low half first
  };

  for (int k = 0; k < 18; ++k) {
    uint64_t m = (uint64_t)next32() * 7ull;
    uint32_t leftover = (uint32_t)m;
    if (leftover < 7u) {
      while (leftover < 4u) { m = (uint64_t)next32() * 7ull; leftover = (uint32_t)m; }
    }
    g_sij[k] = (int)(uint32_t)(m >> 32) - 3;
  }
}

// ---------------- distance: per-patch squared-diff 7x7 stride-2 window sums ----------------
__global__ __launch_bounds__(256) void k_dist(const float* __restrict__ xold) {
  int idx = blockIdx.x * 256 + threadIdx.x;
  if (idx >= NDIST) return;
  int ox = idx % 112; int tt = idx / 112;
  int oy = tt % 112;  tt /= 112;
  int p = tt % 9;     int b = tt / 9;
  int si = g_sij[p], sj = g_sij[9 + p];
  const float* xb = xold + (size_t)b * 3 * 224 * 224;
  float acc = 0.f;
  for (int kh = 0; kh < 7; ++kh) {
    int hb = 2 * oy + kh - 3;
    int hs = hb + si;
    for (int kw = 0; kw < 7; ++kw) {
      int wb = 2 * ox + kw - 3;
      int wsf = wb + sj;
      float s = 0.f;
      for (int c = 0; c < 3; ++c) {
        const float* xc = xb + c * 224 * 224;
        float bv = (hb >= 0 && hb < 224 && wb >= 0 && wb < 224) ? xc[hb * 224 + wb] : 0.f;
        float sv = (hs >= 0 && hs < 224 && wsf >= 0 && wsf < 224) ? xc[hs * 224 + wsf] : 0.f;
        float d = bv - sv;
        s = s + d * d;              // channel sum, in order
      }
      acc = acc + s;                // window sum, row-major order
    }
  }
  g_dist[idx] = acc;
}

// ---------------- global mean: deterministic two-stage reduce ----------------
__global__ __launch_bounds__(256) void k_mean1() {
  __shared__ float red[256];
  int base = blockIdx.x * 4096;
  float acc = 0.f;
  #pragma unroll
  for (int i = 0; i < 4; ++i) {
    float4 v = *(const float4*)(g_dist + base + threadIdx.x * 4 + i * 1024);
    acc = acc + v.x + v.y + v.z + v.w;
  }
  red[threadIdx.x] = acc;
  __syncthreads();
  for (int s = 128; s > 0; s >>= 1) {
    if (threadIdx.x < s) red[threadIdx.x] += red[threadIdx.x + s];
    __syncthreads();
  }
  if (threadIdx.x == 0) g_partial[blockIdx.x] = red[0];
}
__global__ void k_mean2() {
  if (threadIdx.x != 0 || blockIdx.x != 0) return;
  float acc = 0.f;
  for (int i = 0; i < NMEANB; ++i) acc = acc + g_partial[i];
  g_mean[0] = acc / 3612672.0f;
}

// ---------------- pmap = ((sum_p exp(-d/m/2))/9)^2 ----------------
__global__ __launch_bounds__(256) void k_prob1() {
  int idx = blockIdx.x * 256 + threadIdx.x;
  if (idx >= NPMAP) return;
  int xy = idx % 12544; int b = idx / 12544;
  float m = g_mean[0];
  float ssum = 0.f;
  for (int p = 0; p < 9; ++p) {
    float d = g_dist[(size_t)(b * 9 + p) * 12544 + xy];
    float t = (-d / m) / 2.0f;                      // / BW^2 == /1.0 exact
    float e = expf(t);
    ssum = ssum + e;
  }
  float q = ssum / 9.0f;
  g_pmap[idx] = q * q;                              // ** (1/TEMP) == ^2
}

// ---------------- min-pool 3x3 stride 2 pad 1 ----------------
__global__ __launch_bounds__(256) void k_pool() {
  int idx = blockIdx.x * 256 + threadIdx.x;
  if (idx >= NPOOL) return;
  int ox = idx % 56; int tt = idx / 56;
  int oy = tt % 56;  int b = tt / 56;
  float mn = INFINITY;
  for (int kh = 0; kh < 3; ++kh) {
    int y = 2 * oy - 1 + kh; if (y < 0 || y >= 112) continue;
    for (int kw = 0; kw < 3; ++kw) {
      int x = 2 * ox - 1 + kw; if (x < 0 || x >= 112) continue;
      mn = fminf(mn, g_pmap[(size_t)(b * 112 + y) * 112 + x]);
    }
  }
  g_pooled[idx] = mn;
}

// ---------------- per-b row sum (bit-exact sequential order, unchanged) ----------------
__global__ void k_norm1() {
  int b = threadIdx.x;
  if (b >= 32 || blockIdx.x != 0) return;
  const float* P = g_pooled + b * 3136;
  float s = 0.f;
  for (int i = 0; i < 3136; ++i) s = s + P[i];
  g_rowsum[b] = s;
}

// ---------------- logits = logf(p/S + 1e-8) (independent elems, parallel) + row max ----
// Same OCML logf on same inputs -> bit-identical logits; max is order-independent.
__global__ __launch_bounds__(256) void k_norm2() {
  __shared__ float red[4];
  int b = blockIdx.x;                               // 32 blocks
  float s = g_rowsum[b];
  const float* P = g_pooled + b * 3136;
  float lm = -INFINITY;
  for (int i = threadIdx.x; i < 3136; i += 256) {
    float fl = P[i] / s;
    float lg = logf(fl + 1e-8f);
    g_logits[b * 3136 + i] = lg;
    lm = fmaxf(lm, lg);
  }
  #pragma unroll
  for (int off = 32; off; off >>= 1) lm = fmaxf(lm, __shfl_xor(lm, off));
  int wid = threadIdx.x >> 6;
  if ((threadIdx.x & 63) == 0) red[wid] = lm;
  __syncthreads();
  if (threadIdx.x == 0)
    g_lmax[b] = fmaxf(fmaxf(red[0], red[1]), fmaxf(red[2], red[3]));
}

// ---------------- out = x ----------------
__global__ __launch_bounds__(256) void k_copy(const float4* __restrict__ x, float4* __restrict__ out) {
  int i = blockIdx.x * 256 + threadIdx.x;           // 1,605,632 float4 exactly
  out[i] = x[i];
}

// ---------------- JAX threefry2x32, key = (0, 42), partitionable 32-bit bits ----------------
__device__ __forceinline__ uint32_t rotl32(uint32_t x, int r) { return __builtin_rotateleft32(x, r); }
__device__ __forceinline__ void threefry2x32(uint32_t x0, uint32_t x1, uint32_t& o0, uint32_t& o1) {
  const uint32_t ks0 = 0u, ks1 = 42u, ks2 = 0x1BD11BDAu ^ 0u ^ 42u;
  x0 += ks0; x1 += ks1;
#define TFR(r) { x0 += x1; x1 = rotl32(x1, (r)); x1 ^= x0; }
  TFR(13) TFR(15) TFR(26) TFR(6)  x0 += ks1; x1 += ks2 + 1u;
  TFR(17) TFR(29) TFR(16) TFR(24) x0 += ks2; x1 += ks0 + 2u;
  TFR(13) TFR(15) TFR(26) TFR(6)  x0 += ks0; x1 += ks1 + 3u;
  TFR(17) TFR(29) TFR(16) TFR(24) x0 += ks1; x1 += ks2 + 4u;
  TFR(13) TFR(15) TFR(26) TFR(6)  x0 += ks2; x1 += ks0 + 5u;
#undef TFR
  o0 = x0; o1 = x1;
}

__device__ __forceinline__ uint32_t random_bits_at(uint32_t idx) {
  uint32_t o0, o1; threefry2x32(0u, idx, o0, o1);   // counter = (hi,lo) of flat idx
  return o0 ^ o1;                                    // 32-bit partitionable combine
}

// ---- dual threefry, inline-asm, instruction-interleaved (exactly 140 VALU for 2 streams) ----
// VERIFIED R6 (absmax=0). Bit-exact vs threefry2x32: rotl(x,r) == v_alignbit_b32(x,x,32-r);
// ks0=0, ks1=42, ks2=0x1BD11BF0; injections folded to literals; x0+=ks0 (+0) elided.
// Adjacent instrs are independent (A/B alternate) -> chain latency hidden within one wave.
#define TF_R(S) \
  "v_add_u32 %0, %0, %1\n\t" \
  "v_add_u32 %2, %2, %3\n\t" \
  "v_alignbit_b32 %1, %1, %1, " S "\n\t" \
  "v_alignbit_b32 %3, %3, %3, " S "\n\t" \
  "v_xor_b32 %1, %1, %0\n\t" \
  "v_xor_b32 %3, %3, %2\n\t"
#define TF_GX TF_R("19") TF_R("17") TF_R("6") TF_R("26")
#define TF_GY TF_R("15") TF_R("3") TF_R("16") TF_R("8")

__device__ __forceinline__ void tf2_dual(uint32_t inA, uint32_t inB,
                                         uint32_t& outA, uint32_t& outB) {
  uint32_t a0 = 0u, a1 = inA + 42u;                 // x0 += ks0(0), x1 += ks1(42)
  uint32_t b0 = 0u, b1 = inB + 42u;
  asm(TF_GX
      "v_add_u32 %0, 42, %0\n\t"
      "v_add_u32 %2, 42, %2\n\t"
      "v_add_u32 %1, 0x1bd11bf1, %1\n\t"            // ks2+1
      "v_add_u32 %3, 0x1bd11bf1, %3\n\t"
      TF_GY
      "v_add_u32 %0, 0x1bd11bf0, %0\n\t"            // ks2
      "v_add_u32 %2, 0x1bd11bf0, %2\n\t"
      "v_add_u32 %1, 2, %1\n\t"                     // ks0+2
      "v_add_u32 %3, 2, %3\n\t"
      TF_GX
      "v_add_u32 %1, 45, %1\n\t"                    // ks1+3 (x0+=ks0 elided)
      "v_add_u32 %3, 45, %3\n\t"
      TF_GY
      "v_add_u32 %0, 42, %0\n\t"
      "v_add_u32 %2, 42, %2\n\t"
      "v_add_u32 %1, 0x1bd11bf4, %1\n\t"            // ks2+4
      "v_add_u32 %3, 0x1bd11bf4, %3\n\t"
      TF_GX
      "v_add_u32 %0, 0x1bd11bf0, %0\n\t"            // ks2
      "v_add_u32 %2, 0x1bd11bf0, %2\n\t"
      "v_add_u32 %1, 5, %1\n\t"                     // ks0+5
      "v_add_u32 %3, 5, %3\n\t"
      "v_xor_b32 %0, %0, %1\n\t"                    // o0 ^ o1
      "v_xor_b32 %2, %2, %3"
      : "+v"(a0), "+v"(a1), "+v"(b0), "+v"(b1));
  outA = a0; outB = b0;
}

// Exact-value gumbel (OCML logf) -- the winner-deciding path, unchanged from R6.
__device__ __forceinline__ float gumbel_ocml(uint32_t mant) {
  float uni;
  if (mant == 0u) uni = 1.17549435e-38f;            // max(tiny, 0*(1-tiny)+tiny)
  else uni = __uint_as_float(0x3f800000u | mant) - 1.0f;  // exact
  float l1 = logf(uni);
  float n1 = -l1;
  float l2 = logf(n1);
  return -l2;
}

// ==================== categorical sampling: bits-resident scan, zero threefry recompute ====================
//
// One WAVE per (t,h) task; lane l owns {j : j==l mod 64} increasing (verified R5/R6);
// final butterfly (max val, min index on exact ties) == sequential first-occurrence argmax.
//
// Phase 1: asm dual-threefry (exactly once per position -- the bit-exact floor), ALL 25
// per-lane bits kept in registers (fully unrolled, static indices), track per-lane top-1
// (w1, j1) only.
// Phase 2: warm start T0 = wave-max of exact val at each lane's bits-argmax (<= M_final).
//  * bits prescreen B0 = mstar(T0,Lmx)<<9 [R6-VERIFIED formula]: bits < B0 ==> val <=
//    T0-1e-3 < T0 <= M_final -- skip is sound; the true argmax always has bits >= B0
//    (contrapositive), so it survives.
//  * val screen [R3-VERIFIED formula]: gub = fmaf(__log2f(zf), -ln2, 23ln2+1e-3) >=
//    gumbel_ocml(mant); skip iff L[j]+gub <= T0 ==> val < T0 <= M_final. The argmax
//    survives: L+gub >= L+g+9e-4 > T0 when val == M_final >= T0.
//  * survivors (O(1)/task) evaluated with exact gumbel_ocml; (max, min-idx) update.
// No rescan loop exists: threefry computed exactly once per position, ever.

__global__ __launch_bounds__(512) void k_samp() {
  int lane  = threadIdx.x & 63;
  int wtask = blockIdx.x * 8 + (threadIdx.x >> 6);  // wave id == output task id, < NTASK2
  int t = wtask >> 1;               // (s,r) id
  int h = wtask & 1;                // half
  int b = (t & 2047) >> 6;
  const float* Lh = g_logits + b * 3136 + h * 1568;
  float Lmx = g_lmax[b];
  uint32_t vbase = (uint32_t)t * 3136u + (uint32_t)(h * 1568);

  // ---- phase 1: dual-chain threefry, bits kept in registers, top-1 tracking ----
  uint32_t bb[25];
  uint32_t w1; int j1;
  uint32_t vidx = vbase + (uint32_t)lane;
  tf2_dual(vidx, vidx + 64u, bb[0], bb[1]);
  w1 = bb[0]; j1 = lane;
  { bool g = bb[1] > w1; j1 = g ? (lane + 64) : j1; w1 = g ? bb[1] : w1; }
  vidx += 128u;
  #pragma unroll
  for (int k = 1; k < 12; ++k) {
    tf2_dual(vidx, vidx + 64u, bb[2*k], bb[2*k+1]);
    int jA = lane + (k << 7);
    { bool g = bb[2*k]   > w1; j1 = g ? jA        : j1; w1 = g ? bb[2*k]   : w1; }
    { bool g = bb[2*k+1] > w1; j1 = g ? (jA + 64) : j1; w1 = g ? bb[2*k+1] : w1; }
    vidx += 128u;
  }
  {                                 // tail: 1568 = 24*64 + 32, jj = 1536 + lane (lane<32)
    uint32_t x = random_bits_at(vbase + 1536u + (uint32_t)lane);
    x = (lane < 32) ? x : 0u;       // masked lanes can never win (0 > w1 impossible)
    bb[24] = x;
    bool g = x > w1; j1 = g ? (1536 + lane) : j1; w1 = g ? x : w1;
  }

  // ---- phase 2a: warm start + sound bits cutoff ----
  float val1 = Lh[j1] + gumbel_ocml(w1 >> 9);       // exact val of a real position
  float T0 = val1;
  #pragma unroll
  for (int off = 32; off; off >>= 1) T0 = fmaxf(T0, __shfl_xor(T0, off));

  float Tp = T0 - Lmx - 1e-3f;                      // R6-verified margin
  uint32_t mthr = 0u;
  if (Tp > -80.0f) {                                // -inf/NaN safe
    float u_thr = expf(-expf(-Tp));
    int mi = (int)(u_thr * 8388608.0f) - 8;         // R6-verified -8 slack
    mthr = mi > 0 ? (uint32_t)mi : 0u;
  }
  uint32_t B0 = mthr << 9;                          // bits-domain cutoff

  // ---- phase 2b: screened exact evaluation over stored bits ----
  float bestV = -INFINITY; int bestJ = 0x7fffffff;
  #pragma unroll
  for (int k = 0; k < 25; ++k) {
    uint32_t x = bb[k];
    bool pass = (x >= B0);
    if (k == 24) pass = pass && (lane < 32);        // tail guard (B0==0 safety)
    if (__any(pass)) {
      if (pass) {
        int jj = lane + (k << 6);
        uint32_t mant = x >> 9;
        float zf = (float)(0x800000u - mant);       // exact (<= 2^23)
        float gub = fmaf(__log2f(zf), -0.6931472f, 15.943385f);  // 23*ln2 + 1e-3
        float Lj = Lh[jj];
        if (Lj + gub > T0) {                        // R3-verified val screen vs T0<=M
          float v = Lj + gumbel_ocml(mant);
          if (v > bestV || (v == bestV && jj < bestJ)) { bestV = v; bestJ = jj; }
        }
      }
    }
  }

  // ---- wave argmax: max val, min index among exact ties ----
  #pragma unroll
  for (int off = 32; off; off >>= 1) {
    float ov = __shfl_xor(bestV, off);
    int   oj = __shfl_xor(bestJ, off);
    if (ov > bestV || (ov == bestV && oj < bestJ)) { bestV = ov; bestJ = oj; }
  }
  if (lane == 0) {
    g_pM[wtask] = bestV;
    g_pJ[wtask] = h * 1568 + bestJ;                 // absolute j within the row
  }
}

// ---------------- merge halves: strict > keeps first-occurrence argmax ----------------
__global__ __launch_bounds__(256) void k_merge(float* __restrict__ out) {
  int t = blockIdx.x * 256 + threadIdx.x;           // < NSAMP_T (2504*256 exactly)
  float M0 = g_pM[2 * t], M1 = g_pM[2 * t + 1];
  int j = (M1 > M0) ? g_pJ[2 * t + 1] : g_pJ[2 * t];
  int r = t & 2047;
  out[(size_t)r * 3136 + (size_t)j] = 0.0f;
}

// ---------------- launch ----------------
extern "C" void kernel_launch(void* const* d_in, const int* in_sizes, int n_in,
                              void* d_out, int out_size, void* d_ws, size_t ws_size,
                              hipStream_t stream) {
  (void)in_sizes; (void)n_in; (void)d_ws; (void)ws_size; (void)out_size;
  const float* x_old = (const float*)d_in[0];
  const float* x     = (const float*)d_in[1];
  float* out = (float*)d_out;

  k_rng  <<<1,     64, 0, stream>>>();
  k_dist <<<14112, 256, 0, stream>>>(x_old);
  k_mean1<<<NMEANB,256, 0, stream>>>();
  k_mean2<<<1,     64, 0, stream>>>();
  k_prob1<<<1568,  256, 0, stream>>>();
  k_pool <<<392,   256, 0, stream>>>();
  k_norm1<<<1,     64, 0, stream>>>();
  k_norm2<<<32,   256, 0, stream>>>();
  k_copy <<<6272,  256, 0, stream>>>((const float4*)x, (float4*)out);
  k_samp <<<160256, 512, 0, stream>>>();            // one wave per (t,h) task
  k_merge<<<2504,  256, 0, stream>>>(out);
}

// Round 8
// 4615.505 us; speedup vs baseline: 1.3619x; 1.0146x over previous
//
#include <hip/hip_runtime.h>
#include <math.h>
#include <stdint.h>

// Replicate XLA numerics: no FMA contraction anywhere.
#pragma clang fp contract(off)

// ---------------- problem constants ----------------
// x_old: (32,3,224,224) f32; x/out: (32,64,56,56) f32
#define NDIST   3612672   // 32*9*112*112 = 882*4096
#define NPMAP   401408    // 32*112*112
#define NPOOL   100352    // 32*3136
#define NSAMP_T 641024    // 313 * 2048 (one task per (s,r))
#define NMEANB  882       // k_mean1 blocks (4096 elems each)

__device__ __align__(16) float g_dist[NDIST];
__device__ __align__(16) float g_pmap[NPMAP];
__device__ __align__(16) float g_pooled[NPOOL];
__device__ __align__(16) float g_logits[NPOOL];
__device__ float g_partial[NMEANB];
__device__ float g_rowsum[32];
__device__ float g_lmax[32];
__device__ float g_mean[1];
__device__ int   g_sij[18];

// ---------------- NumPy SeedSequence(0) + PCG64 + 32-bit buffered Lemire ----------------
// VERIFIED R6 (absmax=0): mix = x*L - y*R; low-half-first next32; Lemire-32 thr=4;
// initstate = (gs[0]<<64)|gs[1].
__device__ __forceinline__ uint32_t ss_hash(uint32_t value, uint32_t& hc) {
  value ^= hc; hc *= 0x931e8875u; value *= hc; value ^= value >> 16; return value;
}
__device__ __forceinline__ uint32_t ss_mix(uint32_t x, uint32_t y) {
  uint32_t r = x * 0xca01f9ddu - y * 0x4973f715u;   // multiply-SUBTRACT (numpy mix)
  r ^= r >> 16; return r;
}

__global__ void k_rng() {
  if (threadIdx.x != 0 || blockIdx.x != 0) return;
  uint32_t pool[4];
  uint32_t hc = 0x43b0d7e5u;                       // INIT_A
  for (int i = 0; i < 4; ++i) pool[i] = ss_hash(0u, hc);
  for (int is = 0; is < 4; ++is)
    for (int id = 0; id < 4; ++id)
      if (is != id) pool[id] = ss_mix(pool[id], ss_hash(pool[is], hc));
  uint32_t hb = 0x8b51f9ddu;                       // INIT_B
  uint32_t w[8];
  for (int i = 0; i < 8; ++i) {
    uint32_t dv = pool[i & 3];
    dv ^= hb; hb *= 0x58f38dedu; dv *= hb; dv ^= dv >> 16; w[i] = dv;
  }
  uint64_t gs[4];
  for (int i = 0; i < 4; ++i) gs[i] = (uint64_t)w[2*i] | ((uint64_t)w[2*i+1] << 32);
  const __uint128_t MUL = (((__uint128_t)0x2360ED051FC65DA4ull) << 64) | 0x4385DF649FCCF645ull;
  __uint128_t initstate = (((__uint128_t)gs[0]) << 64) | gs[1];
  __uint128_t initseq   = (((__uint128_t)gs[2]) << 64) | gs[3];
  __uint128_t inc   = (initseq << 1) | 1;
  __uint128_t state = 0;
  state = state * MUL + inc;
  state += initstate;
  state = state * MUL + inc;

  bool has32 = false; uint32_t saved32 = 0;
  auto next32 = [&]() -> uint32_t {
    if (has32) { has32 = false; return saved32; }
    state = state * MUL + inc;
    uint64_t xo = (uint64_t)(state >> 64) ^ (uint64_t)state;
    uint32_t rot = (uint32_t)(state >> 122) & 63u;
    uint64_t v = (xo >> rot) | (xo << ((64u - rot) & 63u));   // rotr
    has32 = true; saved32 = (uint32_t)(v >> 32);              // high half buffered
    return (uint32_t)v;                                       // low half first
  };

  for (int k = 0; k < 18; ++k) {
    uint64_t m = (uint64_t)next32() * 7ull;
    uint32_t leftover = (uint32_t)m;
    if (leftover < 7u) {
      while (leftover < 4u) { m = (uint64_t)next32() * 7ull; leftover = (uint32_t)m; }
    }
    g_sij[k] = (int)(uint32_t)(m >> 32) - 3;
  }
}

// ---------------- distance: per-patch squared-diff 7x7 stride-2 window sums ----------------
__global__ __launch_bounds__(256) void k_dist(const float* __restrict__ xold) {
  int idx = blockIdx.x * 256 + threadIdx.x;
  if (idx >= NDIST) return;
  int ox = idx % 112; int tt = idx / 112;
  int oy = tt % 112;  tt /= 112;
  int p = tt % 9;     int b = tt / 9;
  int si = g_sij[p], sj = g_sij[9 + p];
  const float* xb = xold + (size_t)b * 3 * 224 * 224;
  float acc = 0.f;
  for (int kh = 0; kh < 7; ++kh) {
    int hb = 2 * oy + kh - 3;
    int hs = hb + si;
    for (int kw = 0; kw < 7; ++kw) {
      int wb = 2 * ox + kw - 3;
      int wsf = wb + sj;
      float s = 0.f;
      for (int c = 0; c < 3; ++c) {
        const float* xc = xb + c * 224 * 224;
        float bv = (hb >= 0 && hb < 224 && wb >= 0 && wb < 224) ? xc[hb * 224 + wb] : 0.f;
        float sv = (hs >= 0 && hs < 224 && wsf >= 0 && wsf < 224) ? xc[hs * 224 + wsf] : 0.f;
        float d = bv - sv;
        s = s + d * d;              // channel sum, in order
      }
      acc = acc + s;                // window sum, row-major order
    }
  }
  g_dist[idx] = acc;
}

// ---------------- global mean: deterministic two-stage reduce ----------------
__global__ __launch_bounds__(256) void k_mean1() {
  __shared__ float red[256];
  int base = blockIdx.x * 4096;
  float acc = 0.f;
  #pragma unroll
  for (int i = 0; i < 4; ++i) {
    float4 v = *(const float4*)(g_dist + base + threadIdx.x * 4 + i * 1024);
    acc = acc + v.x + v.y + v.z + v.w;
  }
  red[threadIdx.x] = acc;
  __syncthreads();
  for (int s = 128; s > 0; s >>= 1) {
    if (threadIdx.x < s) red[threadIdx.x] += red[threadIdx.x + s];
    __syncthreads();
  }
  if (threadIdx.x == 0) g_partial[blockIdx.x] = red[0];
}
__global__ void k_mean2() {
  if (threadIdx.x != 0 || blockIdx.x != 0) return;
  float acc = 0.f;
  for (int i = 0; i < NMEANB; ++i) acc = acc + g_partial[i];
  g_mean[0] = acc / 3612672.0f;
}

// ---------------- pmap = ((sum_p exp(-d/m/2))/9)^2 ----------------
__global__ __launch_bounds__(256) void k_prob1() {
  int idx = blockIdx.x * 256 + threadIdx.x;
  if (idx >= NPMAP) return;
  int xy = idx % 12544; int b = idx / 12544;
  float m = g_mean[0];
  float ssum = 0.f;
  for (int p = 0; p < 9; ++p) {
    float d = g_dist[(size_t)(b * 9 + p) * 12544 + xy];
    float t = (-d / m) / 2.0f;                      // / BW^2 == /1.0 exact
    float e = expf(t);
    ssum = ssum + e;
  }
  float q = ssum / 9.0f;
  g_pmap[idx] = q * q;                              // ** (1/TEMP) == ^2
}

// ---------------- min-pool 3x3 stride 2 pad 1 ----------------
__global__ __launch_bounds__(256) void k_pool() {
  int idx = blockIdx.x * 256 + threadIdx.x;
  if (idx >= NPOOL) return;
  int ox = idx % 56; int tt = idx / 56;
  int oy = tt % 56;  int b = tt / 56;
  float mn = INFINITY;
  for (int kh = 0; kh < 3; ++kh) {
    int y = 2 * oy - 1 + kh; if (y < 0 || y >= 112) continue;
    for (int kw = 0; kw < 3; ++kw) {
      int x = 2 * ox - 1 + kw; if (x < 0 || x >= 112) continue;
      mn = fminf(mn, g_pmap[(size_t)(b * 112 + y) * 112 + x]);
    }
  }
  g_pooled[idx] = mn;
}

// ---------------- per-b row sum (bit-exact sequential order, unchanged) ----------------
__global__ void k_norm1() {
  int b = threadIdx.x;
  if (b >= 32 || blockIdx.x != 0) return;
  const float* P = g_pooled + b * 3136;
  float s = 0.f;
  for (int i = 0; i < 3136; ++i) s = s + P[i];
  g_rowsum[b] = s;
}

// ---------------- logits = logf(p/S + 1e-8) (independent elems, parallel) + row max ----
// Same OCML logf on same inputs -> bit-identical logits; max is order-independent.
__global__ __launch_bounds__(256) void k_norm2() {
  __shared__ float red[4];
  int b = blockIdx.x;                               // 32 blocks
  float s = g_rowsum[b];
  const float* P = g_pooled + b * 3136;
  float lm = -INFINITY;
  for (int i = threadIdx.x; i < 3136; i += 256) {
    float fl = P[i] / s;
    float lg = logf(fl + 1e-8f);
    g_logits[b * 3136 + i] = lg;
    lm = fmaxf(lm, lg);
  }
  #pragma unroll
  for (int off = 32; off; off >>= 1) lm = fmaxf(lm, __shfl_xor(lm, off));
  int wid = threadIdx.x >> 6;
  if ((threadIdx.x & 63) == 0) red[wid] = lm;
  __syncthreads();
  if (threadIdx.x == 0)
    g_lmax[b] = fmaxf(fmaxf(red[0], red[1]), fmaxf(red[2], red[3]));
}

// ---------------- out = x ----------------
__global__ __launch_bounds__(256) void k_copy(const float4* __restrict__ x, float4* __restrict__ out) {
  int i = blockIdx.x * 256 + threadIdx.x;           // 1,605,632 float4 exactly
  out[i] = x[i];
}

// ---------------- JAX threefry2x32, key = (0, 42), partitionable 32-bit bits ----------------
__device__ __forceinline__ uint32_t rotl32(uint32_t x, int r) { return __builtin_rotateleft32(x, r); }
__device__ __forceinline__ void threefry2x32(uint32_t x0, uint32_t x1, uint32_t& o0, uint32_t& o1) {
  const uint32_t ks0 = 0u, ks1 = 42u, ks2 = 0x1BD11BDAu ^ 0u ^ 42u;
  x0 += ks0; x1 += ks1;
#define TFR(r) { x0 += x1; x1 = rotl32(x1, (r)); x1 ^= x0; }
  TFR(13) TFR(15) TFR(26) TFR(6)  x0 += ks1; x1 += ks2 + 1u;
  TFR(17) TFR(29) TFR(16) TFR(24) x0 += ks2; x1 += ks0 + 2u;
  TFR(13) TFR(15) TFR(26) TFR(6)  x0 += ks0; x1 += ks1 + 3u;
  TFR(17) TFR(29) TFR(16) TFR(24) x0 += ks1; x1 += ks2 + 4u;
  TFR(13) TFR(15) TFR(26) TFR(6)  x0 += ks2; x1 += ks0 + 5u;
#undef TFR
  o0 = x0; o1 = x1;
}

__device__ __forceinline__ uint32_t random_bits_at(uint32_t idx) {
  uint32_t o0, o1; threefry2x32(0u, idx, o0, o1);   // counter = (hi,lo) of flat idx
  return o0 ^ o1;                                    // 32-bit partitionable combine
}

// ---- quad threefry, inline-asm, 4 streams instruction-interleaved (280 VALU / 4 positions) ----
// Bit-exact vs threefry2x32 (same schedule as the R6-VERIFIED dual version, absmax=0):
// rotl(x,r) == v_alignbit_b32(x,x,32-r); ks0=0, ks1=42, ks2=0x1BD11BF0; x0+=ks0 elided.
// Streams a,b,c,d alternate -> dependent ops >=4 instrs apart: zero dep bubbles at any occupancy.
#define TF4_R(S) \
  "v_add_u32 %0, %0, %1\n\t" "v_add_u32 %2, %2, %3\n\t" \
  "v_add_u32 %4, %4, %5\n\t" "v_add_u32 %6, %6, %7\n\t" \
  "v_alignbit_b32 %1, %1, %1, " S "\n\t" "v_alignbit_b32 %3, %3, %3, " S "\n\t" \
  "v_alignbit_b32 %5, %5, %5, " S "\n\t" "v_alignbit_b32 %7, %7, %7, " S "\n\t" \
  "v_xor_b32 %1, %1, %0\n\t" "v_xor_b32 %3, %3, %2\n\t" \
  "v_xor_b32 %5, %5, %4\n\t" "v_xor_b32 %7, %7, %6\n\t"
#define TF4_GX TF4_R("19") TF4_R("17") TF4_R("6") TF4_R("26")
#define TF4_GY TF4_R("15") TF4_R("3") TF4_R("16") TF4_R("8")
#define TF4_I0(L) \
  "v_add_u32 %0, " L ", %0\n\t" "v_add_u32 %2, " L ", %2\n\t" \
  "v_add_u32 %4, " L ", %4\n\t" "v_add_u32 %6, " L ", %6\n\t"
#define TF4_I1(L) \
  "v_add_u32 %1, " L ", %1\n\t" "v_add_u32 %3, " L ", %3\n\t" \
  "v_add_u32 %5, " L ", %5\n\t" "v_add_u32 %7, " L ", %7\n\t"

__device__ __forceinline__ void tf4_quad(uint32_t i0, uint32_t i1, uint32_t i2, uint32_t i3,
                                         uint32_t& o0, uint32_t& o1, uint32_t& o2, uint32_t& o3) {
  uint32_t a0 = 0u, a1 = i0 + 42u;                  // x0 += ks0(0), x1 += ks1(42)
  uint32_t b0 = 0u, b1 = i1 + 42u;
  uint32_t c0 = 0u, c1 = i2 + 42u;
  uint32_t d0 = 0u, d1 = i3 + 42u;
  asm(TF4_GX
      TF4_I0("42")          TF4_I1("0x1bd11bf1")    // ks1 | ks2+1
      TF4_GY
      TF4_I0("0x1bd11bf0")  TF4_I1("2")             // ks2 | ks0+2
      TF4_GX
      TF4_I1("45")                                  // (ks0 elided) | ks1+3
      TF4_GY
      TF4_I0("42")          TF4_I1("0x1bd11bf4")    // ks1 | ks2+4
      TF4_GX
      TF4_I0("0x1bd11bf0")  TF4_I1("5")             // ks2 | ks0+5
      "v_xor_b32 %0, %0, %1\n\t" "v_xor_b32 %2, %2, %3\n\t"
      "v_xor_b32 %4, %4, %5\n\t" "v_xor_b32 %6, %6, %7"
      : "+v"(a0), "+v"(a1), "+v"(b0), "+v"(b1),
        "+v"(c0), "+v"(c1), "+v"(d0), "+v"(d1));
  o0 = a0; o1 = b0; o2 = c0; o3 = d0;
}

// Exact-value gumbel (OCML logf) -- the winner-deciding path, unchanged from R6.
__device__ __forceinline__ float gumbel_ocml(uint32_t mant) {
  float uni;
  if (mant == 0u) uni = 1.17549435e-38f;            // max(tiny, 0*(1-tiny)+tiny)
  else uni = __uint_as_float(0x3f800000u | mant) - 1.0f;  // exact
  float l1 = logf(uni);
  float n1 = -l1;
  float l2 = logf(n1);
  return -l2;
}

// ==================== categorical sampling: one wave per FULL row, rolled quad loop ====================
//
// One WAVE per (s,r) task (3136 = 49*64 exactly -- no ragged tail, no half merge).
// Lane l owns {j : j==l mod 64} in increasing order; final butterfly (max val, min index
// on exact ties) == sequential first-occurrence strict-> argmax [structure verified R5-R7].
//
// Phase 1: ROLLED loop (#pragma unroll 1) of 12 quad-threefry asm blocks (~2.5 KB body,
// I$-resident -- this is the R8 hypothesis test) + 1 full-wave round (j=3072+lane).
// Per lane: top-1 (w1, j1 strict-first) + 2nd-max value w2 [R6-verified update].
// Phase 2 [R6-VERIFIED]: T0 = wave-max of exact val at each lane's bits-argmax (<= M_final);
// B0 = mstar(T0, Lmx)<<9 -- bits < B0 ==> val < T0 <= M_final (sound skip; argmax survives
// by contrapositive). Lane rescans its 49 positions iff w2 >= B0 (else no 2nd candidate
// exists in that lane: bits(j!=j1) <= w2 < B0). Rare (~2%). Lane 0 writes out directly.

#define TOP2_UPD(x, jj) { \
  bool g = (x) > w1; \
  j1 = g ? (jj) : j1; \
  w2 = max(min((x), w1), w2); \
  w1 = max(w1, (x)); }

__global__ __launch_bounds__(256) void k_samp(float* __restrict__ out) {
  int lane  = threadIdx.x & 63;
  int t = blockIdx.x * 4 + (threadIdx.x >> 6);      // wave id == task id, < NSAMP_T exactly
  int r = t & 2047;
  int b = r >> 6;
  const float* L = g_logits + b * 3136;
  float Lmx = g_lmax[b];
  uint32_t vbase = (uint32_t)t * 3136u;             // < 2^31

  // ---- phase 1: rolled quad-threefry top-2 scan ----
  uint32_t w1, w2 = 0u; int j1;
  uint32_t vidx = vbase + (uint32_t)lane;
  {
    uint32_t x0, x1, x2, x3;
    tf4_quad(vidx, vidx + 64u, vidx + 128u, vidx + 192u, x0, x1, x2, x3);
    w1 = x0; j1 = lane;                             // j = lane seeds
    TOP2_UPD(x1, lane + 64)
    TOP2_UPD(x2, lane + 128)
    TOP2_UPD(x3, lane + 192)
    vidx += 256u;
  }
  int jj = lane + 256;
  #pragma unroll 1
  for (int k = 1; k < 12; ++k) {                    // rounds 4..47, j = jj..jj+192
    uint32_t x0, x1, x2, x3;
    tf4_quad(vidx, vidx + 64u, vidx + 128u, vidx + 192u, x0, x1, x2, x3);
    TOP2_UPD(x0, jj)
    TOP2_UPD(x1, jj + 64)
    TOP2_UPD(x2, jj + 128)
    TOP2_UPD(x3, jj + 192)
    vidx += 256u; jj += 256;
  }
  {                                                 // round 48: j = 3072 + lane (full wave)
    uint32_t x = random_bits_at(vbase + 3072u + (uint32_t)lane);
    TOP2_UPD(x, 3072 + lane)
  }

  // ---- phase 2a: warm start + sound bits cutoff [R6-verified] ----
  float val1 = L[j1] + gumbel_ocml(w1 >> 9);        // exact val of a real position
  float T0 = val1;
  #pragma unroll
  for (int off = 32; off; off >>= 1) T0 = fmaxf(T0, __shfl_xor(T0, off));

  float Tp = T0 - Lmx - 1e-3f;                      // R6-verified margin
  uint32_t mthr = 0u;
  if (Tp > -80.0f) {                                // -inf/NaN safe
    float u_thr = expf(-expf(-Tp));
    int mi = (int)(u_thr * 8388608.0f) - 8;         // R6-verified -8 slack
    mthr = mi > 0 ? (uint32_t)mi : 0u;
  }
  uint32_t B0 = mthr << 9;                          // bits-domain cutoff

  float bestV; int bestJ;
  if (w1 >= B0) { bestV = val1; bestJ = j1; }
  else          { bestV = -INFINITY; bestJ = 0x7fffffff; }

  bool flag = (w2 >= B0) || (B0 == 0u);             // lane may hold a 2nd+ candidate
  if (__any(flag)) {
    if (flag) {
      uint32_t vi = vbase + (uint32_t)lane;
      #pragma unroll 1
      for (int k = 0; k < 49; ++k) {
        uint32_t x = random_bits_at(vi);
        if (x >= B0) {
          int j = lane + (k << 6);
          float v = L[j] + gumbel_ocml(x >> 9);
          if (v > bestV || (v == bestV && j < bestJ)) { bestV = v; bestJ = j; }
        }
        vi += 64u;
      }
    }
  }

  // ---- wave argmax: max val, min index among exact ties; direct write ----
  #pragma unroll
  for (int off = 32; off; off >>= 1) {
    float ov = __shfl_xor(bestV, off);
    int   oj = __shfl_xor(bestJ, off);
    if (ov > bestV || (ov == bestV && oj < bestJ)) { bestV = ov; bestJ = oj; }
  }
  if (lane == 0) out[(size_t)r * 3136 + (size_t)bestJ] = 0.0f;
}

// ---------------- launch ----------------
extern "C" void kernel_launch(void* const* d_in, const int* in_sizes, int n_in,
                              void* d_out, int out_size, void* d_ws, size_t ws_size,
                              hipStream_t stream) {
  (void)in_sizes; (void)n_in; (void)d_ws; (void)ws_size; (void)out_size;
  const float* x_old = (const float*)d_in[0];
  const float* x     = (const float*)d_in[1];
  float* out = (float*)d_out;

  k_rng  <<<1,     64, 0, stream>>>();
  k_dist <<<14112, 256, 0, stream>>>(x_old);
  k_mean1<<<NMEANB,256, 0, stream>>>();
  k_mean2<<<1,     64, 0, stream>>>();
  k_prob1<<<1568,  256, 0, stream>>>();
  k_pool <<<392,   256, 0, stream>>>();
  k_norm1<<<1,     64, 0, stream>>>();
  k_norm2<<<32,   256, 0, stream>>>();
  k_copy <<<6272,  256, 0, stream>>>((const float4*)x, (float4*)out);
  k_samp <<<160256, 256, 0, stream>>>(out);         // one wave per (s,r) row, 4 waves/block
}

// Round 9
// 4601.793 us; speedup vs baseline: 1.3659x; 1.0030x over previous
//
#include <hip/hip_runtime.h>
#include <math.h>
#include <stdint.h>

// Replicate XLA numerics: no FMA contraction anywhere.
#pragma clang fp contract(off)

// ---------------- problem constants ----------------
// x_old: (32,3,224,224) f32; x/out: (32,64,56,56) f32
#define NDIST   3612672   // 32*9*112*112 = 882*4096
#define NPMAP   401408    // 32*112*112
#define NPOOL   100352    // 32*3136
#define NSAMP_T 641024    // 313 * 2048 (one task per (s,r))
#define NMEANB  882       // k_mean1 blocks (4096 elems each)

__device__ __align__(16) float g_dist[NDIST];
__device__ __align__(16) float g_pmap[NPMAP];
__device__ __align__(16) float g_pooled[NPOOL];
__device__ __align__(16) float g_logits[NPOOL];
__device__ float g_partial[NMEANB];
__device__ float g_rowsum[32];
__device__ float g_lmax[32];
__device__ float g_mean[1];
__device__ int   g_sij[18];

// ---------------- NumPy SeedSequence(0) + PCG64 + 32-bit buffered Lemire ----------------
// VERIFIED R6 (absmax=0): mix = x*L - y*R; low-half-first next32; Lemire-32 thr=4;
// initstate = (gs[0]<<64)|gs[1].
__device__ __forceinline__ uint32_t ss_hash(uint32_t value, uint32_t& hc) {
  value ^= hc; hc *= 0x931e8875u; value *= hc; value ^= value >> 16; return value;
}
__device__ __forceinline__ uint32_t ss_mix(uint32_t x, uint32_t y) {
  uint32_t r = x * 0xca01f9ddu - y * 0x4973f715u;   // multiply-SUBTRACT (numpy mix)
  r ^= r >> 16; return r;
}

__global__ void k_rng() {
  if (threadIdx.x != 0 || blockIdx.x != 0) return;
  uint32_t pool[4];
  uint32_t hc = 0x43b0d7e5u;                       // INIT_A
  for (int i = 0; i < 4; ++i) pool[i] = ss_hash(0u, hc);
  for (int is = 0; is < 4; ++is)
    for (int id = 0; id < 4; ++id)
      if (is != id) pool[id] = ss_mix(pool[id], ss_hash(pool[is], hc));
  uint32_t hb = 0x8b51f9ddu;                       // INIT_B
  uint32_t w[8];
  for (int i = 0; i < 8; ++i) {
    uint32_t dv = pool[i & 3];
    dv ^= hb; hb *= 0x58f38dedu; dv *= hb; dv ^= dv >> 16; w[i] = dv;
  }
  uint64_t gs[4];
  for (int i = 0; i < 4; ++i) gs[i] = (uint64_t)w[2*i] | ((uint64_t)w[2*i+1] << 32);
  const __uint128_t MUL = (((__uint128_t)0x2360ED051FC65DA4ull) << 64) | 0x4385DF649FCCF645ull;
  __uint128_t initstate = (((__uint128_t)gs[0]) << 64) | gs[1];
  __uint128_t initseq   = (((__uint128_t)gs[2]) << 64) | gs[3];
  __uint128_t inc   = (initseq << 1) | 1;
  __uint128_t state = 0;
  state = state * MUL + inc;
  state += initstate;
  state = state * MUL + inc;

  bool has32 = false; uint32_t saved32 = 0;
  auto next32 = [&]() -> uint32_t {
    if (has32) { has32 = false; return saved32; }
    state = state * MUL + inc;
    uint64_t xo = (uint64_t)(state >> 64) ^ (uint64_t)state;
    uint32_t rot = (uint32_t)(state >> 122) & 63u;
    uint64_t v = (xo >> rot) | (xo << ((64u - rot) & 63u));   // rotr
    has32 = true; saved32 = (uint32_t)(v >> 32);              // high half buffered
    return (uint32_t)v;                                       // low half first
  };

  for (int k = 0; k < 18; ++k) {
    uint64_t m = (uint64_t)next32() * 7ull;
    uint32_t leftover = (uint32_t)m;
    if (leftover < 7u) {
      while (leftover < 4u) { m = (uint64_t)next32() * 7ull; leftover = (uint32_t)m; }
    }
    g_sij[k] = (int)(uint32_t)(m >> 32) - 3;
  }
}

// ---------------- distance: per-patch squared-diff 7x7 stride-2 window sums ----------------
__global__ __launch_bounds__(256) void k_dist(const float* __restrict__ xold) {
  int idx = blockIdx.x * 256 + threadIdx.x;
  if (idx >= NDIST) return;
  int ox = idx % 112; int tt = idx / 112;
  int oy = tt % 112;  tt /= 112;
  int p = tt % 9;     int b = tt / 9;
  int si = g_sij[p], sj = g_sij[9 + p];
  const float* xb = xold + (size_t)b * 3 * 224 * 224;
  float acc = 0.f;
  for (int kh = 0; kh < 7; ++kh) {
    int hb = 2 * oy + kh - 3;
    int hs = hb + si;
    for (int kw = 0; kw < 7; ++kw) {
      int wb = 2 * ox + kw - 3;
      int wsf = wb + sj;
      float s = 0.f;
      for (int c = 0; c < 3; ++c) {
        const float* xc = xb + c * 224 * 224;
        float bv = (hb >= 0 && hb < 224 && wb >= 0 && wb < 224) ? xc[hb * 224 + wb] : 0.f;
        float sv = (hs >= 0 && hs < 224 && wsf >= 0 && wsf < 224) ? xc[hs * 224 + wsf] : 0.f;
        float d = bv - sv;
        s = s + d * d;              // channel sum, in order
      }
      acc = acc + s;                // window sum, row-major order
    }
  }
  g_dist[idx] = acc;
}

// ---------------- global mean: deterministic two-stage reduce ----------------
__global__ __launch_bounds__(256) void k_mean1() {
  __shared__ float red[256];
  int base = blockIdx.x * 4096;
  float acc = 0.f;
  #pragma unroll
  for (int i = 0; i < 4; ++i) {
    float4 v = *(const float4*)(g_dist + base + threadIdx.x * 4 + i * 1024);
    acc = acc + v.x + v.y + v.z + v.w;
  }
  red[threadIdx.x] = acc;
  __syncthreads();
  for (int s = 128; s > 0; s >>= 1) {
    if (threadIdx.x < s) red[threadIdx.x] += red[threadIdx.x + s];
    __syncthreads();
  }
  if (threadIdx.x == 0) g_partial[blockIdx.x] = red[0];
}
__global__ void k_mean2() {
  if (threadIdx.x != 0 || blockIdx.x != 0) return;
  float acc = 0.f;
  for (int i = 0; i < NMEANB; ++i) acc = acc + g_partial[i];
  g_mean[0] = acc / 3612672.0f;
}

// ---------------- pmap = ((sum_p exp(-d/m/2))/9)^2 ----------------
__global__ __launch_bounds__(256) void k_prob1() {
  int idx = blockIdx.x * 256 + threadIdx.x;
  if (idx >= NPMAP) return;
  int xy = idx % 12544; int b = idx / 12544;
  float m = g_mean[0];
  float ssum = 0.f;
  for (int p = 0; p < 9; ++p) {
    float d = g_dist[(size_t)(b * 9 + p) * 12544 + xy];
    float t = (-d / m) / 2.0f;                      // / BW^2 == /1.0 exact
    float e = expf(t);
    ssum = ssum + e;
  }
  float q = ssum / 9.0f;
  g_pmap[idx] = q * q;                              // ** (1/TEMP) == ^2
}

// ---------------- min-pool 3x3 stride 2 pad 1 ----------------
__global__ __launch_bounds__(256) void k_pool() {
  int idx = blockIdx.x * 256 + threadIdx.x;
  if (idx >= NPOOL) return;
  int ox = idx % 56; int tt = idx / 56;
  int oy = tt % 56;  int b = tt / 56;
  float mn = INFINITY;
  for (int kh = 0; kh < 3; ++kh) {
    int y = 2 * oy - 1 + kh; if (y < 0 || y >= 112) continue;
    for (int kw = 0; kw < 3; ++kw) {
      int x = 2 * ox - 1 + kw; if (x < 0 || x >= 112) continue;
      mn = fminf(mn, g_pmap[(size_t)(b * 112 + y) * 112 + x]);
    }
  }
  g_pooled[idx] = mn;
}

// ---------------- per-b row sum (bit-exact sequential order, unchanged) ----------------
__global__ void k_norm1() {
  int b = threadIdx.x;
  if (b >= 32 || blockIdx.x != 0) return;
  const float* P = g_pooled + b * 3136;
  float s = 0.f;
  for (int i = 0; i < 3136; ++i) s = s + P[i];
  g_rowsum[b] = s;
}

// ---------------- logits = logf(p/S + 1e-8) (independent elems, parallel) + row max ----
// Same OCML logf on same inputs -> bit-identical logits; max is order-independent.
__global__ __launch_bounds__(256) void k_norm2() {
  __shared__ float red[4];
  int b = blockIdx.x;                               // 32 blocks
  float s = g_rowsum[b];
  const float* P = g_pooled + b * 3136;
  float lm = -INFINITY;
  for (int i = threadIdx.x; i < 3136; i += 256) {
    float fl = P[i] / s;
    float lg = logf(fl + 1e-8f);
    g_logits[b * 3136 + i] = lg;
    lm = fmaxf(lm, lg);
  }
  #pragma unroll
  for (int off = 32; off; off >>= 1) lm = fmaxf(lm, __shfl_xor(lm, off));
  int wid = threadIdx.x >> 6;
  if ((threadIdx.x & 63) == 0) red[wid] = lm;
  __syncthreads();
  if (threadIdx.x == 0)
    g_lmax[b] = fmaxf(fmaxf(red[0], red[1]), fmaxf(red[2], red[3]));
}

// ---------------- out = x ----------------
__global__ __launch_bounds__(256) void k_copy(const float4* __restrict__ x, float4* __restrict__ out) {
  int i = blockIdx.x * 256 + threadIdx.x;           // 1,605,632 float4 exactly
  out[i] = x[i];
}

// ---------------- JAX threefry2x32, key = (0, 42), partitionable 32-bit bits ----------------
__device__ __forceinline__ uint32_t rotl32(uint32_t x, int r) { return __builtin_rotateleft32(x, r); }
__device__ __forceinline__ void threefry2x32(uint32_t x0, uint32_t x1, uint32_t& o0, uint32_t& o1) {
  const uint32_t ks0 = 0u, ks1 = 42u, ks2 = 0x1BD11BDAu ^ 0u ^ 42u;
  x0 += ks0; x1 += ks1;
#define TFR(r) { x0 += x1; x1 = rotl32(x1, (r)); x1 ^= x0; }
  TFR(13) TFR(15) TFR(26) TFR(6)  x0 += ks1; x1 += ks2 + 1u;
  TFR(17) TFR(29) TFR(16) TFR(24) x0 += ks2; x1 += ks0 + 2u;
  TFR(13) TFR(15) TFR(26) TFR(6)  x0 += ks0; x1 += ks1 + 3u;
  TFR(17) TFR(29) TFR(16) TFR(24) x0 += ks1; x1 += ks2 + 4u;
  TFR(13) TFR(15) TFR(26) TFR(6)  x0 += ks2; x1 += ks0 + 5u;
#undef TFR
  o0 = x0; o1 = x1;
}

__device__ __forceinline__ uint32_t random_bits_at(uint32_t idx) {
  uint32_t o0, o1; threefry2x32(0u, idx, o0, o1);   // counter = (hi,lo) of flat idx
  return o0 ^ o1;                                    // 32-bit partitionable combine
}

// ---- septuple threefry, inline-asm, 7 streams instruction-interleaved ----
// Bit-exact vs threefry2x32 (schedule VERIFIED R6/R8, absmax=0): rotl(x,r) ==
// v_alignbit_b32(x,x,32-r); ks0=0, ks1=42, ks2=0x1BD11BF0; x0+=ks0 elided.
// 7 streams alternate -> dependent ops >=7 instrs apart: zero dep bubbles.
#define TF7_R(S) \
  "v_add_u32 %0, %0, %1\n\t" "v_add_u32 %2, %2, %3\n\t" "v_add_u32 %4, %4, %5\n\t" \
  "v_add_u32 %6, %6, %7\n\t" "v_add_u32 %8, %8, %9\n\t" "v_add_u32 %10, %10, %11\n\t" \
  "v_add_u32 %12, %12, %13\n\t" \
  "v_alignbit_b32 %1, %1, %1, " S "\n\t" "v_alignbit_b32 %3, %3, %3, " S "\n\t" \
  "v_alignbit_b32 %5, %5, %5, " S "\n\t" "v_alignbit_b32 %7, %7, %7, " S "\n\t" \
  "v_alignbit_b32 %9, %9, %9, " S "\n\t" "v_alignbit_b32 %11, %11, %11, " S "\n\t" \
  "v_alignbit_b32 %13, %13, %13, " S "\n\t" \
  "v_xor_b32 %1, %1, %0\n\t" "v_xor_b32 %3, %3, %2\n\t" "v_xor_b32 %5, %5, %4\n\t" \
  "v_xor_b32 %7, %7, %6\n\t" "v_xor_b32 %9, %9, %8\n\t" "v_xor_b32 %11, %11, %10\n\t" \
  "v_xor_b32 %13, %13, %12\n\t"
#define TF7_GX TF7_R("19") TF7_R("17") TF7_R("6") TF7_R("26")
#define TF7_GY TF7_R("15") TF7_R("3") TF7_R("16") TF7_R("8")
#define TF7_I0(L) \
  "v_add_u32 %0, " L ", %0\n\t" "v_add_u32 %2, " L ", %2\n\t" "v_add_u32 %4, " L ", %4\n\t" \
  "v_add_u32 %6, " L ", %6\n\t" "v_add_u32 %8, " L ", %8\n\t" "v_add_u32 %10, " L ", %10\n\t" \
  "v_add_u32 %12, " L ", %12\n\t"
#define TF7_I1(L) \
  "v_add_u32 %1, " L ", %1\n\t" "v_add_u32 %3, " L ", %3\n\t" "v_add_u32 %5, " L ", %5\n\t" \
  "v_add_u32 %7, " L ", %7\n\t" "v_add_u32 %9, " L ", %9\n\t" "v_add_u32 %11, " L ", %11\n\t" \
  "v_add_u32 %13, " L ", %13\n\t"

__device__ __forceinline__ void tf7_sept(uint32_t base,
                                         uint32_t& o0, uint32_t& o1, uint32_t& o2,
                                         uint32_t& o3, uint32_t& o4, uint32_t& o5, uint32_t& o6) {
  uint32_t a0 = 0u, a1 = base + 42u;                // x0 += ks0(0), x1 += ks1(42)
  uint32_t b0 = 0u, b1 = base + 106u;               // +64 + 42
  uint32_t c0 = 0u, c1 = base + 170u;               // +128 + 42
  uint32_t d0 = 0u, d1 = base + 234u;
  uint32_t e0 = 0u, e1 = base + 298u;
  uint32_t f0 = 0u, f1 = base + 362u;
  uint32_t g0 = 0u, g1 = base + 426u;               // +384 + 42
  asm(TF7_GX
      TF7_I0("42")          TF7_I1("0x1bd11bf1")    // ks1 | ks2+1
      TF7_GY
      TF7_I0("0x1bd11bf0")  TF7_I1("2")             // ks2 | ks0+2
      TF7_GX
      TF7_I1("45")                                  // (ks0 elided) | ks1+3
      TF7_GY
      TF7_I0("42")          TF7_I1("0x1bd11bf4")    // ks1 | ks2+4
      TF7_GX
      TF7_I0("0x1bd11bf0")  TF7_I1("5")             // ks2 | ks0+5
      "v_xor_b32 %0, %0, %1\n\t" "v_xor_b32 %2, %2, %3\n\t" "v_xor_b32 %4, %4, %5\n\t"
      "v_xor_b32 %6, %6, %7\n\t" "v_xor_b32 %8, %8, %9\n\t" "v_xor_b32 %10, %10, %11\n\t"
      "v_xor_b32 %12, %12, %13"
      : "+v"(a0), "+v"(a1), "+v"(b0), "+v"(b1), "+v"(c0), "+v"(c1), "+v"(d0), "+v"(d1),
        "+v"(e0), "+v"(e1), "+v"(f0), "+v"(f1), "+v"(g0), "+v"(g1));
  o0 = a0; o1 = b0; o2 = c0; o3 = d0; o4 = e0; o5 = f0; o6 = g0;
}

// Exact-value gumbel (OCML logf) -- the winner-deciding path, unchanged from R6.
__device__ __forceinline__ float gumbel_ocml(uint32_t mant) {
  float uni;
  if (mant == 0u) uni = 1.17549435e-38f;            // max(tiny, 0*(1-tiny)+tiny)
  else uni = __uint_as_float(0x3f800000u | mant) - 1.0f;  // exact
  float l1 = logf(uni);
  float n1 = -l1;
  float l2 = logf(n1);
  return -l2;
}

// ==================== categorical sampling: top-3 scan, recompute only on >=3 passes ====================
//
// One WAVE per (s,r) task (3136 = 49*64 = 7 blocks x 7 streams x 64 lanes; no tail).
// Lane l owns {j : j==l mod 64} increasing; final butterfly (max val, min index on exact
// ties) == sequential first-occurrence strict-> argmax [structure verified R5-R8].
//
// Phase 1: per lane track w1>=w2>=w3 (top-3 bits values, dups counted) and j1 (FIRST
// index of w1), j2 (index of w2). Sorted-insert: w2'=med3(x,w1,w2), w3'=med3(x,w2,w3)
// [exact: med3 == 2nd element of sorted insert], j2' = g1?j1:(g2?jj:j2), j1' = g1?jj:j1,
// w1'=max -- 8 VALU/position.
// Phase 2 [screen formulas VERIFIED R6]: T0 = wave-max exact val at per-lane bits-argmax
// (<= M_final); B0 = mstar(T0,Lmx)<<9: bits<B0 ==> val < T0 <= M_final (sound skip; the
// argmax survives by contrapositive). Per-lane candidate coverage:
//   0 passes (w1<B0): contribute nothing. 1 pass: it is j1 (val1 already computed).
//   2 passes: they are exactly {j1, j2} (a duplicated w2-value would make 3 passes).
//   >=3 passes (w3>=B0, incl. B0==0): full 49-position recompute-rescan (rare: birthday-3).
// Evaluated set = all positions with bits>=B0 ==> contains argmax and all exact ties;
// (max, min-idx) butterfly == first-occurrence argmax. j2 init 0: only evaluable when
// B0<=w2; j=0 is a real position, so a spurious eval is still a genuine (val,idx) <= M.

#define TOP3_UPD(x, jj) { \
  bool g1 = (x) > w1; \
  bool g2 = (x) > w2; \
  uint32_t nw3; asm("v_med3_u32 %0, %1, %2, %3" : "=v"(nw3) : "v"(x), "v"(w2), "v"(w3)); \
  uint32_t nw2; asm("v_med3_u32 %0, %1, %2, %3" : "=v"(nw2) : "v"(x), "v"(w1), "v"(w2)); \
  w3 = nw3; w2 = nw2; \
  j2 = g1 ? j1 : (g2 ? (jj) : j2); \
  j1 = g1 ? (jj) : j1; \
  w1 = max(w1, (x)); }

__global__ __launch_bounds__(256) void k_samp(float* __restrict__ out) {
  int lane  = threadIdx.x & 63;
  int t = blockIdx.x * 4 + (threadIdx.x >> 6);      // wave id == task id, < NSAMP_T exactly
  int r = t & 2047;
  int b = __builtin_amdgcn_readfirstlane(r >> 6);   // wave-uniform -> scalar
  const float* L = g_logits + b * 3136;
  float Lmx = g_lmax[b];
  uint32_t vbase = (uint32_t)t * 3136u;             // < 2^31

  // ---- phase 1: 7 septuple blocks, top-3 tracking ----
  uint32_t w1, w2 = 0u, w3 = 0u; int j1, j2 = 0;
  uint32_t vidx = vbase + (uint32_t)lane;
  {                                                 // block 0 (peeled): j = lane + 64m
    uint32_t x0, x1, x2, x3, x4, x5, x6;
    tf7_sept(vidx, x0, x1, x2, x3, x4, x5, x6);
    w1 = x0; j1 = lane;
    TOP3_UPD(x1, lane + 64)
    TOP3_UPD(x2, lane + 128)
    TOP3_UPD(x3, lane + 192)
    TOP3_UPD(x4, lane + 256)
    TOP3_UPD(x5, lane + 320)
    TOP3_UPD(x6, lane + 384)
    vidx += 448u;
  }
  int jb = lane + 448;
  #pragma unroll 1
  for (int B = 1; B < 7; ++B) {                     // blocks 1..6: j = jb + 64m
    uint32_t x0, x1, x2, x3, x4, x5, x6;
    tf7_sept(vidx, x0, x1, x2, x3, x4, x5, x6);
    TOP3_UPD(x0, jb)
    TOP3_UPD(x1, jb + 64)
    TOP3_UPD(x2, jb + 128)
    TOP3_UPD(x3, jb + 192)
    TOP3_UPD(x4, jb + 256)
    TOP3_UPD(x5, jb + 320)
    TOP3_UPD(x6, jb + 384)
    vidx += 448u; jb += 448;
  }

  // ---- phase 2a: warm start + sound bits cutoff [R6-verified] ----
  float val1 = L[j1] + gumbel_ocml(w1 >> 9);        // exact val of a real position
  float T0 = val1;
  #pragma unroll
  for (int off = 32; off; off >>= 1) T0 = fmaxf(T0, __shfl_xor(T0, off));

  float Tp = T0 - Lmx - 1e-3f;                      // R6-verified margin
  uint32_t mthr = 0u;
  if (Tp > -80.0f) {                                // -inf/NaN safe
    float u_thr = expf(-expf(-Tp));
    int mi = (int)(u_thr * 8388608.0f) - 8;         // R6-verified -8 slack
    mthr = mi > 0 ? (uint32_t)mi : 0u;
  }
  uint32_t B0 = mthr << 9;                          // bits-domain cutoff

  float bestV; int bestJ;
  if (w1 >= B0) { bestV = val1; bestJ = j1; }
  else          { bestV = -INFINITY; bestJ = 0x7fffffff; }

  // ---- phase 2b: direct j2 evaluation (no threefry recompute) ----
  if (__any(w2 >= B0)) {
    if (w2 >= B0) {
      float v2 = L[j2] + gumbel_ocml(w2 >> 9);
      if (v2 > bestV || (v2 == bestV && j2 < bestJ)) { bestV = v2; bestJ = j2; }
    }
  }
  // ---- phase 2c: full recompute-rescan only when a lane has >=3 passes (rare) ----
  bool f3 = (w3 >= B0) || (B0 == 0u);
  if (__any(f3)) {
    if (f3) {
      uint32_t vi = vbase + (uint32_t)lane;
      #pragma unroll 1
      for (int k = 0; k < 49; ++k) {
        uint32_t x = random_bits_at(vi);
        if (x >= B0) {
          int j = lane + (k << 6);
          float v = L[j] + gumbel_ocml(x >> 9);
          if (v > bestV || (v == bestV && j < bestJ)) { bestV = v; bestJ = j; }
        }
        vi += 64u;
      }
    }
  }

  // ---- wave argmax: max val, min index among exact ties; direct write ----
  #pragma unroll
  for (int off = 32; off; off >>= 1) {
    float ov = __shfl_xor(bestV, off);
    int   oj = __shfl_xor(bestJ, off);
    if (ov > bestV || (ov == bestV && oj < bestJ)) { bestV = ov; bestJ = oj; }
  }
  if (lane == 0) out[(size_t)r * 3136 + (size_t)bestJ] = 0.0f;
}

// ---------------- launch ----------------
extern "C" void kernel_launch(void* const* d_in, const int* in_sizes, int n_in,
                              void* d_out, int out_size, void* d_ws, size_t ws_size,
                              hipStream_t stream) {
  (void)in_sizes; (void)n_in; (void)d_ws; (void)ws_size; (void)out_size;
  const float* x_old = (const float*)d_in[0];
  const float* x     = (const float*)d_in[1];
  float* out = (float*)d_out;

  k_rng  <<<1,     64, 0, stream>>>();
  k_dist <<<14112, 256, 0, stream>>>(x_old);
  k_mean1<<<NMEANB,256, 0, stream>>>();
  k_mean2<<<1,     64, 0, stream>>>();
  k_prob1<<<1568,  256, 0, stream>>>();
  k_pool <<<392,   256, 0, stream>>>();
  k_norm1<<<1,     64, 0, stream>>>();
  k_norm2<<<32,   256, 0, stream>>>();
  k_copy <<<6272,  256, 0, stream>>>((const float4*)x, (float4*)out);
  k_samp <<<160256, 256, 0, stream>>>(out);         // one wave per (s,r) row, 4 waves/block
}

// Round 10
// 4394.779 us; speedup vs baseline: 1.4303x; 1.0471x over previous
//
#include <hip/hip_runtime.h>
#include <math.h>
#include <stdint.h>

// Replicate XLA numerics: no FMA contraction anywhere.
#pragma clang fp contract(off)

// ---------------- problem constants ----------------
// x_old: (32,3,224,224) f32; x/out: (32,64,56,56) f32
#define NDIST   3612672   // 32*9*112*112 = 882*4096
#define NPMAP   401408    // 32*112*112
#define NPOOL   100352    // 32*3136
#define NSAMP_T 641024    // 313 * 2048 (one task per (s,r))
#define NMEANB  882       // k_mean1 blocks (4096 elems each)

__device__ __align__(16) float g_dist[NDIST];
__device__ __align__(16) float g_pmap[NPMAP];
__device__ __align__(16) float g_pooled[NPOOL];
__device__ __align__(16) float g_logits[NPOOL];
__device__ float g_partial[NMEANB];
__device__ float g_rowsum[32];
__device__ float g_lmax[32];
__device__ float g_mean[1];
__device__ int   g_sij[18];

// ---------------- NumPy SeedSequence(0) + PCG64 + 32-bit buffered Lemire ----------------
// VERIFIED R6 (absmax=0): mix = x*L - y*R; low-half-first next32; Lemire-32 thr=4;
// initstate = (gs[0]<<64)|gs[1].
__device__ __forceinline__ uint32_t ss_hash(uint32_t value, uint32_t& hc) {
  value ^= hc; hc *= 0x931e8875u; value *= hc; value ^= value >> 16; return value;
}
__device__ __forceinline__ uint32_t ss_mix(uint32_t x, uint32_t y) {
  uint32_t r = x * 0xca01f9ddu - y * 0x4973f715u;   // multiply-SUBTRACT (numpy mix)
  r ^= r >> 16; return r;
}

__global__ void k_rng() {
  if (threadIdx.x != 0 || blockIdx.x != 0) return;
  uint32_t pool[4];
  uint32_t hc = 0x43b0d7e5u;                       // INIT_A
  for (int i = 0; i < 4; ++i) pool[i] = ss_hash(0u, hc);
  for (int is = 0; is < 4; ++is)
    for (int id = 0; id < 4; ++id)
      if (is != id) pool[id] = ss_mix(pool[id], ss_hash(pool[is], hc));
  uint32_t hb = 0x8b51f9ddu;                       // INIT_B
  uint32_t w[8];
  for (int i = 0; i < 8; ++i) {
    uint32_t dv = pool[i & 3];
    dv ^= hb; hb *= 0x58f38dedu; dv *= hb; dv ^= dv >> 16; w[i] = dv;
  }
  uint64_t gs[4];
  for (int i = 0; i < 4; ++i) gs[i] = (uint64_t)w[2*i] | ((uint64_t)w[2*i+1] << 32);
  const __uint128_t MUL = (((__uint128_t)0x2360ED051FC65DA4ull) << 64) | 0x4385DF649FCCF645ull;
  __uint128_t initstate = (((__uint128_t)gs[0]) << 64) | gs[1];
  __uint128_t initseq   = (((__uint128_t)gs[2]) << 64) | gs[3];
  __uint128_t inc   = (initseq << 1) | 1;
  __uint128_t state = 0;
  state = state * MUL + inc;
  state += initstate;
  state = state * MUL + inc;

  bool has32 = false; uint32_t saved32 = 0;
  auto next32 = [&]() -> uint32_t {
    if (has32) { has32 = false; return saved32; }
    state = state * MUL + inc;
    uint64_t xo = (uint64_t)(state >> 64) ^ (uint64_t)state;
    uint32_t rot = (uint32_t)(state >> 122) & 63u;
    uint64_t v = (xo >> rot) | (xo << ((64u - rot) & 63u));   // rotr
    has32 = true; saved32 = (uint32_t)(v >> 32);              // high half buffered
    return (uint32_t)v;                                       // low half first
  };

  for (int k = 0; k < 18; ++k) {
    uint64_t m = (uint64_t)next32() * 7ull;
    uint32_t leftover = (uint32_t)m;
    if (leftover < 7u) {
      while (leftover < 4u) { m = (uint64_t)next32() * 7ull; leftover = (uint32_t)m; }
    }
    g_sij[k] = (int)(uint32_t)(m >> 32) - 3;
  }
}

// ---------------- distance: per-patch squared-diff 7x7 stride-2 window sums ----------------
__global__ __launch_bounds__(256) void k_dist(const float* __restrict__ xold) {
  int idx = blockIdx.x * 256 + threadIdx.x;
  if (idx >= NDIST) return;
  int ox = idx % 112; int tt = idx / 112;
  int oy = tt % 112;  tt /= 112;
  int p = tt % 9;     int b = tt / 9;
  int si = g_sij[p], sj = g_sij[9 + p];
  const float* xb = xold + (size_t)b * 3 * 224 * 224;
  float acc = 0.f;
  for (int kh = 0; kh < 7; ++kh) {
    int hb = 2 * oy + kh - 3;
    int hs = hb + si;
    for (int kw = 0; kw < 7; ++kw) {
      int wb = 2 * ox + kw - 3;
      int wsf = wb + sj;
      float s = 0.f;
      for (int c = 0; c < 3; ++c) {
        const float* xc = xb + c * 224 * 224;
        float bv = (hb >= 0 && hb < 224 && wb >= 0 && wb < 224) ? xc[hb * 224 + wb] : 0.f;
        float sv = (hs >= 0 && hs < 224 && wsf >= 0 && wsf < 224) ? xc[hs * 224 + wsf] : 0.f;
        float d = bv - sv;
        s = s + d * d;              // channel sum, in order
      }
      acc = acc + s;                // window sum, row-major order
    }
  }
  g_dist[idx] = acc;
}

// ---------------- global mean: deterministic two-stage reduce ----------------
__global__ __launch_bounds__(256) void k_mean1() {
  __shared__ float red[256];
  int base = blockIdx.x * 4096;
  float acc = 0.f;
  #pragma unroll
  for (int i = 0; i < 4; ++i) {
    float4 v = *(const float4*)(g_dist + base + threadIdx.x * 4 + i * 1024);
    acc = acc + v.x + v.y + v.z + v.w;
  }
  red[threadIdx.x] = acc;
  __syncthreads();
  for (int s = 128; s > 0; s >>= 1) {
    if (threadIdx.x < s) red[threadIdx.x] += red[threadIdx.x + s];
    __syncthreads();
  }
  if (threadIdx.x == 0) g_partial[blockIdx.x] = red[0];
}
__global__ void k_mean2() {
  if (threadIdx.x != 0 || blockIdx.x != 0) return;
  float acc = 0.f;
  for (int i = 0; i < NMEANB; ++i) acc = acc + g_partial[i];
  g_mean[0] = acc / 3612672.0f;
}

// ---------------- pmap = ((sum_p exp(-d/m/2))/9)^2 ----------------
__global__ __launch_bounds__(256) void k_prob1() {
  int idx = blockIdx.x * 256 + threadIdx.x;
  if (idx >= NPMAP) return;
  int xy = idx % 12544; int b = idx / 12544;
  float m = g_mean[0];
  float ssum = 0.f;
  for (int p = 0; p < 9; ++p) {
    float d = g_dist[(size_t)(b * 9 + p) * 12544 + xy];
    float t = (-d / m) / 2.0f;                      // / BW^2 == /1.0 exact
    float e = expf(t);
    ssum = ssum + e;
  }
  float q = ssum / 9.0f;
  g_pmap[idx] = q * q;                              // ** (1/TEMP) == ^2
}

// ---------------- min-pool 3x3 stride 2 pad 1 ----------------
__global__ __launch_bounds__(256) void k_pool() {
  int idx = blockIdx.x * 256 + threadIdx.x;
  if (idx >= NPOOL) return;
  int ox = idx % 56; int tt = idx / 56;
  int oy = tt % 56;  int b = tt / 56;
  float mn = INFINITY;
  for (int kh = 0; kh < 3; ++kh) {
    int y = 2 * oy - 1 + kh; if (y < 0 || y >= 112) continue;
    for (int kw = 0; kw < 3; ++kw) {
      int x = 2 * ox - 1 + kw; if (x < 0 || x >= 112) continue;
      mn = fminf(mn, g_pmap[(size_t)(b * 112 + y) * 112 + x]);
    }
  }
  g_pooled[idx] = mn;
}

// ---------------- per-b row sum (bit-exact sequential order, unchanged) ----------------
__global__ void k_norm1() {
  int b = threadIdx.x;
  if (b >= 32 || blockIdx.x != 0) return;
  const float* P = g_pooled + b * 3136;
  float s = 0.f;
  for (int i = 0; i < 3136; ++i) s = s + P[i];
  g_rowsum[b] = s;
}

// ---------------- logits = logf(p/S + 1e-8) (independent elems, parallel) + row max ----
// Same OCML logf on same inputs -> bit-identical logits; max is order-independent.
__global__ __launch_bounds__(256) void k_norm2() {
  __shared__ float red[4];
  int b = blockIdx.x;                               // 32 blocks
  float s = g_rowsum[b];
  const float* P = g_pooled + b * 3136;
  float lm = -INFINITY;
  for (int i = threadIdx.x; i < 3136; i += 256) {
    float fl = P[i] / s;
    float lg = logf(fl + 1e-8f);
    g_logits[b * 3136 + i] = lg;
    lm = fmaxf(lm, lg);
  }
  #pragma unroll
  for (int off = 32; off; off >>= 1) lm = fmaxf(lm, __shfl_xor(lm, off));
  int wid = threadIdx.x >> 6;
  if ((threadIdx.x & 63) == 0) red[wid] = lm;
  __syncthreads();
  if (threadIdx.x == 0)
    g_lmax[b] = fmaxf(fmaxf(red[0], red[1]), fmaxf(red[2], red[3]));
}

// ---------------- out = x ----------------
__global__ __launch_bounds__(256) void k_copy(const float4* __restrict__ x, float4* __restrict__ out) {
  int i = blockIdx.x * 256 + threadIdx.x;           // 1,605,632 float4 exactly
  out[i] = x[i];
}

// ---------------- JAX threefry2x32, key = (0, 42), partitionable 32-bit bits ----------------
__device__ __forceinline__ uint32_t rotl32(uint32_t x, int r) { return __builtin_rotateleft32(x, r); }
__device__ __forceinline__ void threefry2x32(uint32_t x0, uint32_t x1, uint32_t& o0, uint32_t& o1) {
  const uint32_t ks0 = 0u, ks1 = 42u, ks2 = 0x1BD11BDAu ^ 0u ^ 42u;
  x0 += ks0; x1 += ks1;
#define TFR(r) { x0 += x1; x1 = rotl32(x1, (r)); x1 ^= x0; }
  TFR(13) TFR(15) TFR(26) TFR(6)  x0 += ks1; x1 += ks2 + 1u;
  TFR(17) TFR(29) TFR(16) TFR(24) x0 += ks2; x1 += ks0 + 2u;
  TFR(13) TFR(15) TFR(26) TFR(6)  x0 += ks0; x1 += ks1 + 3u;
  TFR(17) TFR(29) TFR(16) TFR(24) x0 += ks1; x1 += ks2 + 4u;
  TFR(13) TFR(15) TFR(26) TFR(6)  x0 += ks2; x1 += ks0 + 5u;
#undef TFR
  o0 = x0; o1 = x1;
}

__device__ __forceinline__ uint32_t random_bits_at(uint32_t idx) {
  uint32_t o0, o1; threefry2x32(0u, idx, o0, o1);   // counter = (hi,lo) of flat idx
  return o0 ^ o1;                                    // 32-bit partitionable combine
}

// ---- septuple threefry, inline-asm, 7 streams instruction-interleaved ----
// Bit-exact vs threefry2x32 (schedule VERIFIED R6/R8/R9, absmax=0): rotl(x,r) ==
// v_alignbit_b32(x,x,32-r); ks0=0, ks1=42, ks2=0x1BD11BF0; x0+=ks0 elided.
// 7 streams alternate -> dependent ops >=7 instrs apart: zero dep bubbles.
#define TF7_R(S) \
  "v_add_u32 %0, %0, %1\n\t" "v_add_u32 %2, %2, %3\n\t" "v_add_u32 %4, %4, %5\n\t" \
  "v_add_u32 %6, %6, %7\n\t" "v_add_u32 %8, %8, %9\n\t" "v_add_u32 %10, %10, %11\n\t" \
  "v_add_u32 %12, %12, %13\n\t" \
  "v_alignbit_b32 %1, %1, %1, " S "\n\t" "v_alignbit_b32 %3, %3, %3, " S "\n\t" \
  "v_alignbit_b32 %5, %5, %5, " S "\n\t" "v_alignbit_b32 %7, %7, %7, " S "\n\t" \
  "v_alignbit_b32 %9, %9, %9, " S "\n\t" "v_alignbit_b32 %11, %11, %11, " S "\n\t" \
  "v_alignbit_b32 %13, %13, %13, " S "\n\t" \
  "v_xor_b32 %1, %1, %0\n\t" "v_xor_b32 %3, %3, %2\n\t" "v_xor_b32 %5, %5, %4\n\t" \
  "v_xor_b32 %7, %7, %6\n\t" "v_xor_b32 %9, %9, %8\n\t" "v_xor_b32 %11, %11, %10\n\t" \
  "v_xor_b32 %13, %13, %12\n\t"
#define TF7_GX TF7_R("19") TF7_R("17") TF7_R("6") TF7_R("26")
#define TF7_GY TF7_R("15") TF7_R("3") TF7_R("16") TF7_R("8")
#define TF7_I0(L) \
  "v_add_u32 %0, " L ", %0\n\t" "v_add_u32 %2, " L ", %2\n\t" "v_add_u32 %4, " L ", %4\n\t" \
  "v_add_u32 %6, " L ", %6\n\t" "v_add_u32 %8, " L ", %8\n\t" "v_add_u32 %10, " L ", %10\n\t" \
  "v_add_u32 %12, " L ", %12\n\t"
#define TF7_I1(L) \
  "v_add_u32 %1, " L ", %1\n\t" "v_add_u32 %3, " L ", %3\n\t" "v_add_u32 %5, " L ", %5\n\t" \
  "v_add_u32 %7, " L ", %7\n\t" "v_add_u32 %9, " L ", %9\n\t" "v_add_u32 %11, " L ", %11\n\t" \
  "v_add_u32 %13, " L ", %13\n\t"

__device__ __forceinline__ void tf7_sept(uint32_t base,
                                         uint32_t& o0, uint32_t& o1, uint32_t& o2,
                                         uint32_t& o3, uint32_t& o4, uint32_t& o5, uint32_t& o6) {
  uint32_t a0 = 0u, a1 = base + 42u;                // x0 += ks0(0), x1 += ks1(42)
  uint32_t b0 = 0u, b1 = base + 106u;               // +64 + 42
  uint32_t c0 = 0u, c1 = base + 170u;               // +128 + 42
  uint32_t d0 = 0u, d1 = base + 234u;
  uint32_t e0 = 0u, e1 = base + 298u;
  uint32_t f0 = 0u, f1 = base + 362u;
  uint32_t g0 = 0u, g1 = base + 426u;               // +384 + 42
  asm(TF7_GX
      TF7_I0("42")          TF7_I1("0x1bd11bf1")    // ks1 | ks2+1
      TF7_GY
      TF7_I0("0x1bd11bf0")  TF7_I1("2")             // ks2 | ks0+2
      TF7_GX
      TF7_I1("45")                                  // (ks0 elided) | ks1+3
      TF7_GY
      TF7_I0("42")          TF7_I1("0x1bd11bf4")    // ks1 | ks2+4
      TF7_GX
      TF7_I0("0x1bd11bf0")  TF7_I1("5")             // ks2 | ks0+5
      "v_xor_b32 %0, %0, %1\n\t" "v_xor_b32 %2, %2, %3\n\t" "v_xor_b32 %4, %4, %5\n\t"
      "v_xor_b32 %6, %6, %7\n\t" "v_xor_b32 %8, %8, %9\n\t" "v_xor_b32 %10, %10, %11\n\t"
      "v_xor_b32 %12, %12, %13"
      : "+v"(a0), "+v"(a1), "+v"(b0), "+v"(b1), "+v"(c0), "+v"(c1), "+v"(d0), "+v"(d1),
        "+v"(e0), "+v"(e1), "+v"(f0), "+v"(f1), "+v"(g0), "+v"(g1));
  o0 = a0; o1 = b0; o2 = c0; o3 = d0; o4 = e0; o5 = f0; o6 = g0;
}

// Exact-value gumbel (OCML logf) -- the winner-deciding path, unchanged from R6.
__device__ __forceinline__ float gumbel_ocml(uint32_t mant) {
  float uni;
  if (mant == 0u) uni = 1.17549435e-38f;            // max(tiny, 0*(1-tiny)+tiny)
  else uni = __uint_as_float(0x3f800000u | mant) - 1.0f;  // exact
  float l1 = logf(uni);
  float n1 = -l1;
  float l2 = logf(n1);
  return -l2;
}

// ==================== categorical sampling: TOP1 + bits-resident + exact prescreen ====================
//
// One WAVE per (s,r) task (3136 = 49*64 = 7 blocks x 7 streams x 64 lanes; no tail).
// Lane l owns {j : j==l mod 64} increasing; final butterfly (max val, min index on exact
// ties) == sequential first-occurrence strict-> argmax [structure verified R5-R9].
//
// Phase 1 (floor-stripped): septuple asm threefry leaves ALL 49 per-lane bits live in
// named registers (zero extra instructions); tracking is TOP1 only -- 3 VALU/slot
// (v_cmp, v_cndmask on j, v_max). Static count ~74 wave-instr/slot vs the 71-instr
// threefry floor.
// Phase 2 [screen formulas VERIFIED R6]: T0 = wave-max of exact val at each lane's
// bits-argmax (<= M_final); B0 = mstar(T0,Lmx)<<9: bits < B0 ==> val < T0 <= M_final.
// Evaluated set = EXACTLY {j : bits_j >= B0} via 49 unrolled register compares
// (v_cmp + s_cbranch_vccz per slot; body fires for ~2-4 slots/task since expected
// passes P ~ e^{-T0} * sum e^{L_j} = O(1)). Soundness/completeness:
//   - skipped j has bits < B0 ==> val < T0 <= M_final: cannot win or tie.
//   - the T0-achieving lane's bits >= B0 (contrapositive) ==> evaluated set nonempty
//     and contains the argmax and all exact ties of M_final.
//   - re-evaluating j1 is a no-op under (v > bestV) || (v == bestV && j < bestJ).
// (max val, min idx) butterfly == first-occurrence argmax. Lane 0 writes out directly.

#define TOP1_UPD(x, jj) { \
  bool g = (x) > w1; \
  j1 = g ? (jj) : j1; \
  w1 = max(w1, (x)); }

#define SEPT_BLOCK(B) { \
  tf7_sept(vb + (uint32_t)((B) * 448), \
           bb[(B)*7], bb[(B)*7+1], bb[(B)*7+2], bb[(B)*7+3], \
           bb[(B)*7+4], bb[(B)*7+5], bb[(B)*7+6]); \
  TOP1_UPD(bb[(B)*7],   lane + (B)*448) \
  TOP1_UPD(bb[(B)*7+1], lane + (B)*448 + 64) \
  TOP1_UPD(bb[(B)*7+2], lane + (B)*448 + 128) \
  TOP1_UPD(bb[(B)*7+3], lane + (B)*448 + 192) \
  TOP1_UPD(bb[(B)*7+4], lane + (B)*448 + 256) \
  TOP1_UPD(bb[(B)*7+5], lane + (B)*448 + 320) \
  TOP1_UPD(bb[(B)*7+6], lane + (B)*448 + 384) }

__global__ __launch_bounds__(256) void k_samp(float* __restrict__ out) {
  int lane  = threadIdx.x & 63;
  int t = blockIdx.x * 4 + (threadIdx.x >> 6);      // wave id == task id, < NSAMP_T exactly
  int r = t & 2047;
  int b = __builtin_amdgcn_readfirstlane(r >> 6);   // wave-uniform -> scalar
  const float* L = g_logits + b * 3136;
  float Lmx = g_lmax[b];
  uint32_t vb = (uint32_t)t * 3136u + (uint32_t)lane;   // lane's stream base, < 2^31

  // ---- phase 1: 7 septuple blocks, bits kept live, TOP1 tracking ----
  uint32_t bb[49];
  uint32_t w1; int j1;
  {                                                 // block 0 (seeds w1/j1 from slot 0)
    tf7_sept(vb, bb[0], bb[1], bb[2], bb[3], bb[4], bb[5], bb[6]);
    w1 = bb[0]; j1 = lane;
    TOP1_UPD(bb[1], lane + 64)
    TOP1_UPD(bb[2], lane + 128)
    TOP1_UPD(bb[3], lane + 192)
    TOP1_UPD(bb[4], lane + 256)
    TOP1_UPD(bb[5], lane + 320)
    TOP1_UPD(bb[6], lane + 384)
  }
  SEPT_BLOCK(1)
  SEPT_BLOCK(2)
  SEPT_BLOCK(3)
  SEPT_BLOCK(4)
  SEPT_BLOCK(5)
  SEPT_BLOCK(6)

  // ---- phase 2a: warm start + sound bits cutoff [R6-verified] ----
  float val1 = L[j1] + gumbel_ocml(w1 >> 9);        // exact val of a real position
  float T0 = val1;
  #pragma unroll
  for (int off = 32; off; off >>= 1) T0 = fmaxf(T0, __shfl_xor(T0, off));

  float Tp = T0 - Lmx - 1e-3f;                      // R6-verified margin
  uint32_t mthr = 0u;
  if (Tp > -80.0f) {                                // -inf/NaN safe
    float u_thr = expf(-expf(-Tp));
    int mi = (int)(u_thr * 8388608.0f) - 8;         // R6-verified -8 slack
    mthr = mi > 0 ? (uint32_t)mi : 0u;
  }
  uint32_t B0 = mthr << 9;                          // bits-domain cutoff

  // ---- phase 2b: exact evaluation of {j : bits_j >= B0} over stored registers ----
  float bestV = -INFINITY; int bestJ = 0x7fffffff;
  #pragma unroll
  for (int k = 0; k < 49; ++k) {
    bool pass = (bb[k] >= B0);
    if (__any(pass)) {                              // rare: ~2-4 of 49 slots fire
      if (pass) {
        int jj = lane + (k << 6);
        float v = L[jj] + gumbel_ocml(bb[k] >> 9);
        if (v > bestV || (v == bestV && jj < bestJ)) { bestV = v; bestJ = jj; }
      }
    }
  }

  // ---- wave argmax: max val, min index among exact ties; direct write ----
  #pragma unroll
  for (int off = 32; off; off >>= 1) {
    float ov = __shfl_xor(bestV, off);
    int   oj = __shfl_xor(bestJ, off);
    if (ov > bestV || (ov == bestV && oj < bestJ)) { bestV = ov; bestJ = oj; }
  }
  if (lane == 0) out[(size_t)r * 3136 + (size_t)bestJ] = 0.0f;
}

// ---------------- launch ----------------
extern "C" void kernel_launch(void* const* d_in, const int* in_sizes, int n_in,
                              void* d_out, int out_size, void* d_ws, size_t ws_size,
                              hipStream_t stream) {
  (void)in_sizes; (void)n_in; (void)d_ws; (void)ws_size; (void)out_size;
  const float* x_old = (const float*)d_in[0];
  const float* x     = (const float*)d_in[1];
  float* out = (float*)d_out;

  k_rng  <<<1,     64, 0, stream>>>();
  k_dist <<<14112, 256, 0, stream>>>(x_old);
  k_mean1<<<NMEANB,256, 0, stream>>>();
  k_mean2<<<1,     64, 0, stream>>>();
  k_prob1<<<1568,  256, 0, stream>>>();
  k_pool <<<392,   256, 0, stream>>>();
  k_norm1<<<1,     64, 0, stream>>>();
  k_norm2<<<32,   256, 0, stream>>>();
  k_copy <<<6272,  256, 0, stream>>>((const float4*)x, (float4*)out);
  k_samp <<<160256, 256, 0, stream>>>(out);         // one wave per (s,r) row, 4 waves/block
}

// Round 11
// 4361.643 us; speedup vs baseline: 1.4412x; 1.0076x over previous
//
#include <hip/hip_runtime.h>
#include <math.h>
#include <stdint.h>

// Replicate XLA numerics: no FMA contraction anywhere.
#pragma clang fp contract(off)

// ---------------- problem constants ----------------
// x_old: (32,3,224,224) f32; x/out: (32,64,56,56) f32
#define NDIST   3612672   // 32*9*112*112 = 882*4096
#define NPMAP   401408    // 32*112*112
#define NPOOL   100352    // 32*3136
#define NSAMP_T 641024    // 313 * 2048 (one task per (s,r))
#define NMEANB  882       // k_mean1 blocks (4096 elems each)

__device__ __align__(16) float g_dist[NDIST];
__device__ __align__(16) float g_pmap[NPMAP];
__device__ __align__(16) float g_pooled[NPOOL];
__device__ __align__(16) float g_logits[NPOOL];
__device__ float g_partial[NMEANB];
__device__ float g_rowsum[32];
__device__ float g_lmax[32];
__device__ float g_mean[1];
__device__ int   g_sij[18];

// ---------------- NumPy SeedSequence(0) + PCG64 + 32-bit buffered Lemire ----------------
// VERIFIED R6 (absmax=0): mix = x*L - y*R; low-half-first next32; Lemire-32 thr=4;
// initstate = (gs[0]<<64)|gs[1].
__device__ __forceinline__ uint32_t ss_hash(uint32_t value, uint32_t& hc) {
  value ^= hc; hc *= 0x931e8875u; value *= hc; value ^= value >> 16; return value;
}
__device__ __forceinline__ uint32_t ss_mix(uint32_t x, uint32_t y) {
  uint32_t r = x * 0xca01f9ddu - y * 0x4973f715u;   // multiply-SUBTRACT (numpy mix)
  r ^= r >> 16; return r;
}

__global__ void k_rng() {
  if (threadIdx.x != 0 || blockIdx.x != 0) return;
  uint32_t pool[4];
  uint32_t hc = 0x43b0d7e5u;                       // INIT_A
  for (int i = 0; i < 4; ++i) pool[i] = ss_hash(0u, hc);
  for (int is = 0; is < 4; ++is)
    for (int id = 0; id < 4; ++id)
      if (is != id) pool[id] = ss_mix(pool[id], ss_hash(pool[is], hc));
  uint32_t hb = 0x8b51f9ddu;                       // INIT_B
  uint32_t w[8];
  for (int i = 0; i < 8; ++i) {
    uint32_t dv = pool[i & 3];
    dv ^= hb; hb *= 0x58f38dedu; dv *= hb; dv ^= dv >> 16; w[i] = dv;
  }
  uint64_t gs[4];
  for (int i = 0; i < 4; ++i) gs[i] = (uint64_t)w[2*i] | ((uint64_t)w[2*i+1] << 32);
  const __uint128_t MUL = (((__uint128_t)0x2360ED051FC65DA4ull) << 64) | 0x4385DF649FCCF645ull;
  __uint128_t initstate = (((__uint128_t)gs[0]) << 64) | gs[1];
  __uint128_t initseq   = (((__uint128_t)gs[2]) << 64) | gs[3];
  __uint128_t inc   = (initseq << 1) | 1;
  __uint128_t state = 0;
  state = state * MUL + inc;
  state += initstate;
  state = state * MUL + inc;

  bool has32 = false; uint32_t saved32 = 0;
  auto next32 = [&]() -> uint32_t {
    if (has32) { has32 = false; return saved32; }
    state = state * MUL + inc;
    uint64_t xo = (uint64_t)(state >> 64) ^ (uint64_t)state;
    uint32_t rot = (uint32_t)(state >> 122) & 63u;
    uint64_t v = (xo >> rot) | (xo << ((64u - rot) & 63u));   // rotr
    has32 = true; saved32 = (uint32_t)(v >> 32);              // high half buffered
    return (uint32_t)v;                                       // low half first
  };

  for (int k = 0; k < 18; ++k) {
    uint64_t m = (uint64_t)next32() * 7ull;
    uint32_t leftover = (uint32_t)m;
    if (leftover < 7u) {
      while (leftover < 4u) { m = (uint64_t)next32() * 7ull; leftover = (uint32_t)m; }
    }
    g_sij[k] = (int)(uint32_t)(m >> 32) - 3;
  }
}

// ---------------- distance: per-patch squared-diff 7x7 stride-2 window sums ----------------
__global__ __launch_bounds__(256) void k_dist(const float* __restrict__ xold) {
  int idx = blockIdx.x * 256 + threadIdx.x;
  if (idx >= NDIST) return;
  int ox = idx % 112; int tt = idx / 112;
  int oy = tt % 112;  tt /= 112;
  int p = tt % 9;     int b = tt / 9;
  int si = g_sij[p], sj = g_sij[9 + p];
  const float* xb = xold + (size_t)b * 3 * 224 * 224;
  float acc = 0.f;
  for (int kh = 0; kh < 7; ++kh) {
    int hb = 2 * oy + kh - 3;
    int hs = hb + si;
    for (int kw = 0; kw < 7; ++kw) {
      int wb = 2 * ox + kw - 3;
      int wsf = wb + sj;
      float s = 0.f;
      for (int c = 0; c < 3; ++c) {
        const float* xc = xb + c * 224 * 224;
        float bv = (hb >= 0 && hb < 224 && wb >= 0 && wb < 224) ? xc[hb * 224 + wb] : 0.f;
        float sv = (hs >= 0 && hs < 224 && wsf >= 0 && wsf < 224) ? xc[hs * 224 + wsf] : 0.f;
        float d = bv - sv;
        s = s + d * d;              // channel sum, in order
      }
      acc = acc + s;                // window sum, row-major order
    }
  }
  g_dist[idx] = acc;
}

// ---------------- global mean: deterministic two-stage reduce ----------------
__global__ __launch_bounds__(256) void k_mean1() {
  __shared__ float red[256];
  int base = blockIdx.x * 4096;
  float acc = 0.f;
  #pragma unroll
  for (int i = 0; i < 4; ++i) {
    float4 v = *(const float4*)(g_dist + base + threadIdx.x * 4 + i * 1024);
    acc = acc + v.x + v.y + v.z + v.w;
  }
  red[threadIdx.x] = acc;
  __syncthreads();
  for (int s = 128; s > 0; s >>= 1) {
    if (threadIdx.x < s) red[threadIdx.x] += red[threadIdx.x + s];
    __syncthreads();
  }
  if (threadIdx.x == 0) g_partial[blockIdx.x] = red[0];
}
__global__ void k_mean2() {
  if (threadIdx.x != 0 || blockIdx.x != 0) return;
  float acc = 0.f;
  for (int i = 0; i < NMEANB; ++i) acc = acc + g_partial[i];
  g_mean[0] = acc / 3612672.0f;
}

// ---------------- pmap = ((sum_p exp(-d/m/2))/9)^2 ----------------
__global__ __launch_bounds__(256) void k_prob1() {
  int idx = blockIdx.x * 256 + threadIdx.x;
  if (idx >= NPMAP) return;
  int xy = idx % 12544; int b = idx / 12544;
  float m = g_mean[0];
  float ssum = 0.f;
  for (int p = 0; p < 9; ++p) {
    float d = g_dist[(size_t)(b * 9 + p) * 12544 + xy];
    float t = (-d / m) / 2.0f;                      // / BW^2 == /1.0 exact
    float e = expf(t);
    ssum = ssum + e;
  }
  float q = ssum / 9.0f;
  g_pmap[idx] = q * q;                              // ** (1/TEMP) == ^2
}

// ---------------- min-pool 3x3 stride 2 pad 1 ----------------
__global__ __launch_bounds__(256) void k_pool() {
  int idx = blockIdx.x * 256 + threadIdx.x;
  if (idx >= NPOOL) return;
  int ox = idx % 56; int tt = idx / 56;
  int oy = tt % 56;  int b = tt / 56;
  float mn = INFINITY;
  for (int kh = 0; kh < 3; ++kh) {
    int y = 2 * oy - 1 + kh; if (y < 0 || y >= 112) continue;
    for (int kw = 0; kw < 3; ++kw) {
      int x = 2 * ox - 1 + kw; if (x < 0 || x >= 112) continue;
      mn = fminf(mn, g_pmap[(size_t)(b * 112 + y) * 112 + x]);
    }
  }
  g_pooled[idx] = mn;
}

// ---------------- per-b row sum (bit-exact sequential order, unchanged) ----------------
__global__ void k_norm1() {
  int b = threadIdx.x;
  if (b >= 32 || blockIdx.x != 0) return;
  const float* P = g_pooled + b * 3136;
  float s = 0.f;
  for (int i = 0; i < 3136; ++i) s = s + P[i];
  g_rowsum[b] = s;
}

// ---------------- logits = logf(p/S + 1e-8) (independent elems, parallel) + row max ----
// Same OCML logf on same inputs -> bit-identical logits; max is order-independent.
__global__ __launch_bounds__(256) void k_norm2() {
  __shared__ float red[4];
  int b = blockIdx.x;                               // 32 blocks
  float s = g_rowsum[b];
  const float* P = g_pooled + b * 3136;
  float lm = -INFINITY;
  for (int i = threadIdx.x; i < 3136; i += 256) {
    float fl = P[i] / s;
    float lg = logf(fl + 1e-8f);
    g_logits[b * 3136 + i] = lg;
    lm = fmaxf(lm, lg);
  }
  #pragma unroll
  for (int off = 32; off; off >>= 1) lm = fmaxf(lm, __shfl_xor(lm, off));
  int wid = threadIdx.x >> 6;
  if ((threadIdx.x & 63) == 0) red[wid] = lm;
  __syncthreads();
  if (threadIdx.x == 0)
    g_lmax[b] = fmaxf(fmaxf(red[0], red[1]), fmaxf(red[2], red[3]));
}

// ---------------- out = x ----------------
__global__ __launch_bounds__(256) void k_copy(const float4* __restrict__ x, float4* __restrict__ out) {
  int i = blockIdx.x * 256 + threadIdx.x;           // 1,605,632 float4 exactly
  out[i] = x[i];
}

// ---------------- JAX threefry2x32, key = (0, 42), partitionable 32-bit bits ----------------
__device__ __forceinline__ uint32_t rotl32(uint32_t x, int r) { return __builtin_rotateleft32(x, r); }
__device__ __forceinline__ void threefry2x32(uint32_t x0, uint32_t x1, uint32_t& o0, uint32_t& o1) {
  const uint32_t ks0 = 0u, ks1 = 42u, ks2 = 0x1BD11BDAu ^ 0u ^ 42u;
  x0 += ks0; x1 += ks1;
#define TFR(r) { x0 += x1; x1 = rotl32(x1, (r)); x1 ^= x0; }
  TFR(13) TFR(15) TFR(26) TFR(6)  x0 += ks1; x1 += ks2 + 1u;
  TFR(17) TFR(29) TFR(16) TFR(24) x0 += ks2; x1 += ks0 + 2u;
  TFR(13) TFR(15) TFR(26) TFR(6)  x0 += ks0; x1 += ks1 + 3u;
  TFR(17) TFR(29) TFR(16) TFR(24) x0 += ks1; x1 += ks2 + 4u;
  TFR(13) TFR(15) TFR(26) TFR(6)  x0 += ks2; x1 += ks0 + 5u;
#undef TFR
  o0 = x0; o1 = x1;
}

__device__ __forceinline__ uint32_t random_bits_at(uint32_t idx) {
  uint32_t o0, o1; threefry2x32(0u, idx, o0, o1);   // counter = (hi,lo) of flat idx
  return o0 ^ o1;                                    // 32-bit partitionable combine
}

// ---- septuple threefry, inline-asm, 7 streams instruction-interleaved ----
// Bit-exact vs threefry2x32 (schedule VERIFIED R6/R8/R9/R10, absmax=0): rotl(x,r) ==
// v_alignbit_b32(x,x,32-r); ks0=0, ks1=42, ks2=0x1BD11BF0; x0+=ks0 elided.
// 7 streams alternate -> dependent ops >=7 instrs apart: zero dep bubbles.
#define TF7_R(S) \
  "v_add_u32 %0, %0, %1\n\t" "v_add_u32 %2, %2, %3\n\t" "v_add_u32 %4, %4, %5\n\t" \
  "v_add_u32 %6, %6, %7\n\t" "v_add_u32 %8, %8, %9\n\t" "v_add_u32 %10, %10, %11\n\t" \
  "v_add_u32 %12, %12, %13\n\t" \
  "v_alignbit_b32 %1, %1, %1, " S "\n\t" "v_alignbit_b32 %3, %3, %3, " S "\n\t" \
  "v_alignbit_b32 %5, %5, %5, " S "\n\t" "v_alignbit_b32 %7, %7, %7, " S "\n\t" \
  "v_alignbit_b32 %9, %9, %9, " S "\n\t" "v_alignbit_b32 %11, %11, %11, " S "\n\t" \
  "v_alignbit_b32 %13, %13, %13, " S "\n\t" \
  "v_xor_b32 %1, %1, %0\n\t" "v_xor_b32 %3, %3, %2\n\t" "v_xor_b32 %5, %5, %4\n\t" \
  "v_xor_b32 %7, %7, %6\n\t" "v_xor_b32 %9, %9, %8\n\t" "v_xor_b32 %11, %11, %10\n\t" \
  "v_xor_b32 %13, %13, %12\n\t"
#define TF7_GX TF7_R("19") TF7_R("17") TF7_R("6") TF7_R("26")
#define TF7_GY TF7_R("15") TF7_R("3") TF7_R("16") TF7_R("8")
#define TF7_I0(L) \
  "v_add_u32 %0, " L ", %0\n\t" "v_add_u32 %2, " L ", %2\n\t" "v_add_u32 %4, " L ", %4\n\t" \
  "v_add_u32 %6, " L ", %6\n\t" "v_add_u32 %8, " L ", %8\n\t" "v_add_u32 %10, " L ", %10\n\t" \
  "v_add_u32 %12, " L ", %12\n\t"
#define TF7_I1(L) \
  "v_add_u32 %1, " L ", %1\n\t" "v_add_u32 %3, " L ", %3\n\t" "v_add_u32 %5, " L ", %5\n\t" \
  "v_add_u32 %7, " L ", %7\n\t" "v_add_u32 %9, " L ", %9\n\t" "v_add_u32 %11, " L ", %11\n\t" \
  "v_add_u32 %13, " L ", %13\n\t"

__device__ __forceinline__ void tf7_sept(uint32_t base,
                                         uint32_t& o0, uint32_t& o1, uint32_t& o2,
                                         uint32_t& o3, uint32_t& o4, uint32_t& o5, uint32_t& o6) {
  uint32_t a0 = 0u, a1 = base + 42u;                // x0 += ks0(0), x1 += ks1(42)
  uint32_t b0 = 0u, b1 = base + 106u;               // +64 + 42
  uint32_t c0 = 0u, c1 = base + 170u;               // +128 + 42
  uint32_t d0 = 0u, d1 = base + 234u;
  uint32_t e0 = 0u, e1 = base + 298u;
  uint32_t f0 = 0u, f1 = base + 362u;
  uint32_t g0 = 0u, g1 = base + 426u;               // +384 + 42
  asm(TF7_GX
      TF7_I0("42")          TF7_I1("0x1bd11bf1")    // ks1 | ks2+1
      TF7_GY
      TF7_I0("0x1bd11bf0")  TF7_I1("2")             // ks2 | ks0+2
      TF7_GX
      TF7_I1("45")                                  // (ks0 elided) | ks1+3
      TF7_GY
      TF7_I0("42")          TF7_I1("0x1bd11bf4")    // ks1 | ks2+4
      TF7_GX
      TF7_I0("0x1bd11bf0")  TF7_I1("5")             // ks2 | ks0+5
      "v_xor_b32 %0, %0, %1\n\t" "v_xor_b32 %2, %2, %3\n\t" "v_xor_b32 %4, %4, %5\n\t"
      "v_xor_b32 %6, %6, %7\n\t" "v_xor_b32 %8, %8, %9\n\t" "v_xor_b32 %10, %10, %11\n\t"
      "v_xor_b32 %12, %12, %13"
      : "+v"(a0), "+v"(a1), "+v"(b0), "+v"(b1), "+v"(c0), "+v"(c1), "+v"(d0), "+v"(d1),
        "+v"(e0), "+v"(e1), "+v"(f0), "+v"(f1), "+v"(g0), "+v"(g1));
  o0 = a0; o1 = b0; o2 = c0; o3 = d0; o4 = e0; o5 = f0; o6 = g0;
}

// Exact-value gumbel (OCML logf) -- the winner-deciding path, unchanged from R6.
__device__ __forceinline__ float gumbel_ocml(uint32_t mant) {
  float uni;
  if (mant == 0u) uni = 1.17549435e-38f;            // max(tiny, 0*(1-tiny)+tiny)
  else uni = __uint_as_float(0x3f800000u | mant) - 1.0f;  // exact
  float l1 = logf(uni);
  float n1 = -l1;
  float l2 = logf(n1);
  return -l2;
}

// ==================== categorical sampling: packed top-2 keys, branch-free phases ====================
//
// One WAVE per (s,r) task (3136 = 49*64 = 7 blocks x 7 streams x 64 lanes; no tail).
// Lane l owns {j : j==l mod 64} increasing; final butterfly (max val, min index on exact
// ties) == sequential first-occurrence strict-> argmax [structure verified R5-R10].
//
// Phase 1 (branch-free, 4 VALU/slot): packed key K_k = (bits_k & 0xFFFFFE00) | (63-k).
// gumbel uses only mant = bits>>9, so K-order == (mant, smaller-k-first) order; low 9
// bits of K hold 63-k (k<=48 -> 63-k in [15,63], bits 6-8 zero). Track w1 = max K and
// w2 = 2nd-max K (sorted-insert: w2 = max(min(K,w1), w2); w1 = max(w1,K)). Keys are
// distinct (distinct k) -> w2 is the true 2nd max.
// Phase 2 [screen formulas VERIFIED R6]:
//  * recover mant1 = w1>>9 (== bits>>9 of the argmax slot), k1 = 63-(w1&511),
//    j1 = lane + (k1<<6); val1 = L[j1] + gumbel_ocml(mant1) -- exact val of a real
//    position; T0 = wave-max val1 <= M_final. B0 = mstar(T0,Lmx)<<9 [R6 margin+slack]:
//    bits < B0 ==> val < T0 <= M_final (sound skip; argmax survives by contrapositive).
//  * B0 is 512-aligned, packed low bits < 512 ==> (w1 >= B0 <=> max bits passes) and
//    (w2 >= B0 <=> lane has >= 2 passing positions).
//  * exactly-1-pass lane: that pass IS j1 (max-bits position) -- already evaluated as
//    val1; no work. >=2 passes (or B0==0, since w2 >= 0): stored-bits scan of all 49
//    slots, evaluating every bits >= B0 with (>, min-idx) updates -- covers all
//    candidates in first-occurrence-correct order; re-evaluating j1 is a no-op.
// (max val, min idx) butterfly == first-occurrence argmax. Lane 0 writes out directly.

#define TOP2P(x, C) { \
  uint32_t K = ((x) & 0xFFFFFE00u) | (uint32_t)(C); \
  w2 = max(min(K, w1), w2); \
  w1 = max(w1, K); }

#define SEPT_BLOCK(B) { \
  tf7_sept(vb + (uint32_t)((B) * 448), \
           bb[(B)*7], bb[(B)*7+1], bb[(B)*7+2], bb[(B)*7+3], \
           bb[(B)*7+4], bb[(B)*7+5], bb[(B)*7+6]); \
  TOP2P(bb[(B)*7],   63 - (B)*7) \
  TOP2P(bb[(B)*7+1], 62 - (B)*7) \
  TOP2P(bb[(B)*7+2], 61 - (B)*7) \
  TOP2P(bb[(B)*7+3], 60 - (B)*7) \
  TOP2P(bb[(B)*7+4], 59 - (B)*7) \
  TOP2P(bb[(B)*7+5], 58 - (B)*7) \
  TOP2P(bb[(B)*7+6], 57 - (B)*7) }

__global__ __launch_bounds__(256) void k_samp(float* __restrict__ out) {
  int lane  = threadIdx.x & 63;
  int t = blockIdx.x * 4 + (threadIdx.x >> 6);      // wave id == task id, < NSAMP_T exactly
  int r = t & 2047;
  int b = __builtin_amdgcn_readfirstlane(r >> 6);   // wave-uniform -> scalar
  const float* L = g_logits + b * 3136;
  float Lmx = g_lmax[b];
  uint32_t vb = (uint32_t)t * 3136u + (uint32_t)lane;   // lane's stream base, < 2^31

  // ---- phase 1: 7 septuple blocks, bits kept live, packed top-2 tracking ----
  uint32_t bb[49];
  uint32_t w1, w2 = 0u;
  {                                                 // block 0 (slot 0 seeds w1)
    tf7_sept(vb, bb[0], bb[1], bb[2], bb[3], bb[4], bb[5], bb[6]);
    w1 = (bb[0] & 0xFFFFFE00u) | 63u;
    TOP2P(bb[1], 62)
    TOP2P(bb[2], 61)
    TOP2P(bb[3], 60)
    TOP2P(bb[4], 59)
    TOP2P(bb[5], 58)
    TOP2P(bb[6], 57)
  }
  SEPT_BLOCK(1)
  SEPT_BLOCK(2)
  SEPT_BLOCK(3)
  SEPT_BLOCK(4)
  SEPT_BLOCK(5)
  SEPT_BLOCK(6)

  // ---- phase 2a: recover per-lane argmax, warm start + sound bits cutoff [R6-verified] ----
  uint32_t mant1 = w1 >> 9;                         // == bits>>9 at the argmax slot
  int j1 = lane + ((63 - (int)(w1 & 511u)) << 6);   // k1 = 63 - low bits
  float val1 = L[j1] + gumbel_ocml(mant1);          // exact val of a real position
  float T0 = val1;
  #pragma unroll
  for (int off = 32; off; off >>= 1) T0 = fmaxf(T0, __shfl_xor(T0, off));

  float Tp = T0 - Lmx - 1e-3f;                      // R6-verified margin
  uint32_t mthr = 0u;
  if (Tp > -80.0f) {                                // -inf/NaN safe
    float u_thr = expf(-expf(-Tp));
    int mi = (int)(u_thr * 8388608.0f) - 8;         // R6-verified -8 slack
    mthr = mi > 0 ? (uint32_t)mi : 0u;
  }
  uint32_t B0 = mthr << 9;                          // bits-domain cutoff (512-aligned)

  float bestV; int bestJ;
  if (w1 >= B0) { bestV = val1; bestJ = j1; }       // lane's max-bits position passes
  else          { bestV = -INFINITY; bestJ = 0x7fffffff; }

  // ---- phase 2b: stored-bits scan ONLY for lanes with >=2 passes (w2 >= B0) ----
  // (B0 == 0 ==> w2 >= B0 for all lanes ==> sound full-scan fallback.)
  bool multi = (w2 >= B0);
  if (__any(multi)) {                               // rare: ~5-10% of waves
    if (multi) {
      #pragma unroll
      for (int k = 0; k < 49; ++k) {
        if (bb[k] >= B0) {
          int jj = lane + (k << 6);
          float v = L[jj] + gumbel_ocml(bb[k] >> 9);
          if (v > bestV || (v == bestV && jj < bestJ)) { bestV = v; bestJ = jj; }
        }
      }
    }
  }

  // ---- wave argmax: max val, min index among exact ties; direct write ----
  #pragma unroll
  for (int off = 32; off; off >>= 1) {
    float ov = __shfl_xor(bestV, off);
    int   oj = __shfl_xor(bestJ, off);
    if (ov > bestV || (ov == bestV && oj < bestJ)) { bestV = ov; bestJ = oj; }
  }
  if (lane == 0) out[(size_t)r * 3136 + (size_t)bestJ] = 0.0f;
}

// ---------------- launch ----------------
extern "C" void kernel_launch(void* const* d_in, const int* in_sizes, int n_in,
                              void* d_out, int out_size, void* d_ws, size_t ws_size,
                              hipStream_t stream) {
  (void)in_sizes; (void)n_in; (void)d_ws; (void)ws_size; (void)out_size;
  const float* x_old = (const float*)d_in[0];
  const float* x     = (const float*)d_in[1];
  float* out = (float*)d_out;

  k_rng  <<<1,     64, 0, stream>>>();
  k_dist <<<14112, 256, 0, stream>>>(x_old);
  k_mean1<<<NMEANB,256, 0, stream>>>();
  k_mean2<<<1,     64, 0, stream>>>();
  k_prob1<<<1568,  256, 0, stream>>>();
  k_pool <<<392,   256, 0, stream>>>();
  k_norm1<<<1,     64, 0, stream>>>();
  k_norm2<<<32,   256, 0, stream>>>();
  k_copy <<<6272,  256, 0, stream>>>((const float4*)x, (float4*)out);
  k_samp <<<160256, 256, 0, stream>>>(out);         // one wave per (s,r) row, 4 waves/block
}